// Round 6
// baseline (413.167 us; speedup 1.0000x reference)
//
#include <hip/hip_runtime.h>

#define HIDDEN_C 64
#define NCHUNK 64

__device__ __forceinline__ float4 f4zero() { return make_float4(0.f, 0.f, 0.f, 0.f); }

#define SWZ(node) ((((node) >> 2) & 7) << 4)

// ---------------- generic exclusive scan (blocksum -> scanpartial -> writeptr) ----------------
__global__ __launch_bounds__(256) void k_blocksum(const int* __restrict__ deg,
                                                  int* __restrict__ partial, int n) {
    int base = blockIdx.x * 1024 + threadIdx.x * 4;
    int s = 0;
#pragma unroll
    for (int k = 0; k < 4; ++k) {
        int i = base + k;
        if (i < n) s += deg[i];
    }
    __shared__ int red[256];
    red[threadIdx.x] = s;
    __syncthreads();
    for (int d = 128; d > 0; d >>= 1) {
        if (threadIdx.x < d) red[threadIdx.x] += red[threadIdx.x + d];
        __syncthreads();
    }
    if (threadIdx.x == 0) partial[blockIdx.x] = red[0];
}

__global__ __launch_bounds__(256) void k_scanpartial(int* __restrict__ partial,
                                                     int* __restrict__ last_slot,
                                                     int nBlocks, int nE) {
    __shared__ int buf[256];
    int tid = threadIdx.x;
    int v = (tid < nBlocks) ? partial[tid] : 0;
    buf[tid] = v;
    __syncthreads();
    for (int d = 1; d < 256; d <<= 1) {
        int t = (tid >= d) ? buf[tid - d] : 0;
        __syncthreads();
        buf[tid] += t;
        __syncthreads();
    }
    if (tid < nBlocks) partial[tid] = buf[tid] - v;
    if (tid == 0) last_slot[0] = nE;
}

__global__ __launch_bounds__(256) void k_writeptr(const int* __restrict__ deg,
                                                  const int* __restrict__ partial,
                                                  int* __restrict__ outp,
                                                  int* __restrict__ outp2, int n) {
    int tid = threadIdx.x;
    int base = blockIdx.x * 1024 + tid * 4;
    int d[4];
    int s = 0;
#pragma unroll
    for (int k = 0; k < 4; ++k) {
        int i = base + k;
        d[k] = (i < n) ? deg[i] : 0;
        s += d[k];
    }
    __shared__ int buf[256];
    buf[tid] = s;
    __syncthreads();
    for (int dd = 1; dd < 256; dd <<= 1) {
        int t = (tid >= dd) ? buf[tid - dd] : 0;
        __syncthreads();
        buf[tid] += t;
        __syncthreads();
    }
    int off = partial[blockIdx.x] + buf[tid] - s;
#pragma unroll
    for (int k = 0; k < 4; ++k) {
        int i = base + k;
        if (i < n) {
            outp[i] = off;
            outp2[i] = off;
            off += d[k];
        }
    }
}

// ---------------- bucket partition (bucket = dst>>6) ----------------
__global__ __launch_bounds__(256) void k_bcount(const int* __restrict__ dst,
                                                int* __restrict__ cnt,
                                                int nE, int chunkSz, int nBuckets) {
    __shared__ int h[1024];
    int c = blockIdx.x, tid = threadIdx.x;
    for (int i = tid; i < nBuckets; i += 256) h[i] = 0;
    __syncthreads();
    int beg = c * chunkSz;
    int end = beg + chunkSz; if (end > nE) end = nE;
    for (int e = beg + tid; e < end; e += 256) atomicAdd(&h[dst[e] >> 6], 1);
    __syncthreads();
    for (int i = tid; i < nBuckets; i += 256) cnt[i * NCHUNK + c] = h[i];
}

__global__ __launch_bounds__(256) void k_bscatter(const int* __restrict__ src,
                                                  const int* __restrict__ dst,
                                                  const int* __restrict__ eoff,
                                                  unsigned* __restrict__ ebuf,
                                                  int nE, int chunkSz, int nBuckets) {
    __shared__ int cur[1024];
    int c = blockIdx.x, tid = threadIdx.x;
    for (int i = tid; i < nBuckets; i += 256) cur[i] = eoff[i * NCHUNK + c];
    __syncthreads();
    int beg = c * chunkSz;
    int end = beg + chunkSz; if (end > nE) end = nE;
    for (int e = beg + tid; e < end; e += 256) {
        int d = dst[e];
        int b = d >> 6;
        int pos = atomicAdd(&cur[b], 1);
        ebuf[pos] = ((unsigned)(d & 63) << 16) | (unsigned)src[e];  // nNodes<=65536
    }
}

// one block per bucket: local hist+scan -> rowptr + dst-sorted col (contiguous 4KB region)
__global__ __launch_bounds__(256) void k_bfill(const unsigned* __restrict__ ebuf,
                                               const int* __restrict__ eoff,
                                               int* __restrict__ rowptr,
                                               int* __restrict__ col,
                                               int nNodes, int nE, int nBuckets) {
    __shared__ int deg[64], cur[64];
    int b = blockIdx.x, tid = threadIdx.x;
    int lo = eoff[b * NCHUNK];
    int hi = (b + 1 < nBuckets) ? eoff[(b + 1) * NCHUNK] : nE;
    if (tid < 64) deg[tid] = 0;
    __syncthreads();
    for (int e = lo + tid; e < hi; e += 256) atomicAdd(&deg[ebuf[e] >> 16], 1);
    __syncthreads();
    if (tid < 64) {
        int d = deg[tid];
        int s = d;
        for (int o = 1; o < 64; o <<= 1) {
            int t = __shfl_up(s, o, 64);
            if (tid >= o) s += t;
        }
        int st = s - d;  // exclusive
        cur[tid] = lo + st;
        int node = b * 64 + tid;
        if (node < nNodes) rowptr[node] = lo + st;
    }
    __syncthreads();
    for (int e = lo + tid; e < hi; e += 256) {
        unsigned pk = ebuf[e];
        int pos = atomicAdd(&cur[pk >> 16], 1);
        col[pos] = (int)(pk & 0xFFFFu);
    }
}

// ---------------- fused BN(prev) + gather + 2-layer MLP + BN-stats ----------------
#define KSTEP(AC, WV)                                                       \
    acc00 = fmaf(a0.AC, WV.x, acc00); acc01 = fmaf(a0.AC, WV.y, acc01);     \
    acc02 = fmaf(a0.AC, WV.z, acc02); acc03 = fmaf(a0.AC, WV.w, acc03);     \
    acc10 = fmaf(a1.AC, WV.x, acc10); acc11 = fmaf(a1.AC, WV.y, acc11);     \
    acc12 = fmaf(a1.AC, WV.z, acc12); acc13 = fmaf(a1.AC, WV.w, acc13);     \
    acc20 = fmaf(a2.AC, WV.x, acc20); acc21 = fmaf(a2.AC, WV.y, acc21);     \
    acc22 = fmaf(a2.AC, WV.z, acc22); acc23 = fmaf(a2.AC, WV.w, acc23);     \
    acc30 = fmaf(a3.AC, WV.x, acc30); acc31 = fmaf(a3.AC, WV.y, acc31);     \
    acc32 = fmaf(a3.AC, WV.z, acc32); acc33 = fmaf(a3.AC, WV.w, acc33);

// unroll 4: keeps in-flight b128 loads bounded so VGPR stays under the occupancy cap
#define GEMM_LOOP(SRC)                                                                     \
    _Pragma("unroll 4")                                                                    \
    for (int kb = 0; kb < 16; ++kb) {                                                      \
        int kB = kb * 16;                                                                  \
        float4 a0 = *(const float4*)((const char*)SRC + (nr + 0) * 256 + (kB ^ SWZ(nr + 0))); \
        float4 a1 = *(const float4*)((const char*)SRC + (nr + 1) * 256 + (kB ^ SWZ(nr + 1))); \
        float4 a2 = *(const float4*)((const char*)SRC + (nr + 2) * 256 + (kB ^ SWZ(nr + 2))); \
        float4 a3 = *(const float4*)((const char*)SRC + (nr + 3) * 256 + (kB ^ SWZ(nr + 3))); \
        const char* wrow = (const char*)sW + kb * 1024 + fc * 4;                           \
        float4 w0 = *(const float4*)(wrow);                                               \
        float4 w1 = *(const float4*)(wrow + 256);                                         \
        float4 w2 = *(const float4*)(wrow + 512);                                         \
        float4 w3 = *(const float4*)(wrow + 768);                                         \
        KSTEP(x, w0) KSTEP(y, w1) KSTEP(z, w2) KSTEP(w, w3)                                \
    }

template <bool DOBN>
__global__ __launch_bounds__(256, 3) void k_layer(const float* __restrict__ x,
                                                  const int* __restrict__ rowptr,
                                                  const int* __restrict__ col,
                                                  const float4* __restrict__ W1_4,
                                                  const float* __restrict__ b1,
                                                  const float4* __restrict__ W2_4,
                                                  const float* __restrict__ b2,
                                                  const float* __restrict__ statsP,
                                                  const float* __restrict__ gammaP,
                                                  const float* __restrict__ betaP,
                                                  float* __restrict__ statsO,
                                                  float4* __restrict__ h_out4,
                                                  int nNodes, float invN) {
    __shared__ float sA[4096];
    __shared__ float sW[4096];
    __shared__ float sH1[4096];

    int tid = threadIdx.x;
    int n0 = blockIdx.x * 64;
    int lane = tid & 63;
    int w = tid >> 6;

    float scb = 1.f, shb = 0.f;
    if (DOBN) {
        float m = statsP[lane] * invN;
        float var = statsP[64 + lane] * invN - m * m;
        scb = gammaP[lane] * rsqrtf(var + 1e-5f);
        shb = betaP[lane] - m * scb;
    }

#pragma unroll
    for (int it = 0; it < 4; ++it) ((float4*)sW)[it * 256 + tid] = W1_4[it * 256 + tid];

    // gather: wave w handles local rows {4i + w}; lane = feature
    for (int i = 0; i < 16; ++i) {
        int r = i * 4 + w;
        int node = n0 + r;
        float acc = 0.f;
        if (node < nNodes) {
            int lo = rowptr[node], hi = rowptr[node + 1];
            float v = x[(size_t)node * 64 + lane];
            acc = DOBN ? fmaxf(fmaf(v, scb, shb), 0.f) : v;
            for (int e0 = lo; e0 < hi; e0 += 64) {
                int mye = e0 + lane;
                int cs = (mye < hi) ? col[mye] : 0;
                int m2 = hi - e0; if (m2 > 64) m2 = 64;
                int j = 0;
                for (; j + 3 < m2; j += 4) {
                    int s0 = __shfl(cs, j, 64);
                    int s1 = __shfl(cs, j + 1, 64);
                    int s2 = __shfl(cs, j + 2, 64);
                    int s3 = __shfl(cs, j + 3, 64);
                    float v0 = x[(size_t)s0 * 64 + lane];
                    float v1 = x[(size_t)s1 * 64 + lane];
                    float v2 = x[(size_t)s2 * 64 + lane];
                    float v3 = x[(size_t)s3 * 64 + lane];
                    if (DOBN) {
                        v0 = fmaxf(fmaf(v0, scb, shb), 0.f);
                        v1 = fmaxf(fmaf(v1, scb, shb), 0.f);
                        v2 = fmaxf(fmaf(v2, scb, shb), 0.f);
                        v3 = fmaxf(fmaf(v3, scb, shb), 0.f);
                    }
                    acc += v0; acc += v1; acc += v2; acc += v3;
                }
                for (; j < m2; ++j) {
                    int s0 = __shfl(cs, j, 64);
                    float v0 = x[(size_t)s0 * 64 + lane];
                    if (DOBN) v0 = fmaxf(fmaf(v0, scb, shb), 0.f);
                    acc += v0;
                }
            }
        }
        *(float*)((char*)sA + r * 256 + ((lane * 4) ^ SWZ(r))) = acc;
    }
    __syncthreads();

    int nr = (tid >> 4) * 4;
    int fc = (tid & 15) * 4;

    float4 bias = ((const float4*)b1)[tid & 15];
    float acc00 = bias.x, acc01 = bias.y, acc02 = bias.z, acc03 = bias.w;
    float acc10 = bias.x, acc11 = bias.y, acc12 = bias.z, acc13 = bias.w;
    float acc20 = bias.x, acc21 = bias.y, acc22 = bias.z, acc23 = bias.w;
    float acc30 = bias.x, acc31 = bias.y, acc32 = bias.z, acc33 = bias.w;

    GEMM_LOOP(sA)

    {
        float4 r;
        r.x = fmaxf(acc00, 0.f); r.y = fmaxf(acc01, 0.f); r.z = fmaxf(acc02, 0.f); r.w = fmaxf(acc03, 0.f);
        *(float4*)((char*)sH1 + (nr + 0) * 256 + ((fc * 4) ^ SWZ(nr + 0))) = r;
        r.x = fmaxf(acc10, 0.f); r.y = fmaxf(acc11, 0.f); r.z = fmaxf(acc12, 0.f); r.w = fmaxf(acc13, 0.f);
        *(float4*)((char*)sH1 + (nr + 1) * 256 + ((fc * 4) ^ SWZ(nr + 1))) = r;
        r.x = fmaxf(acc20, 0.f); r.y = fmaxf(acc21, 0.f); r.z = fmaxf(acc22, 0.f); r.w = fmaxf(acc23, 0.f);
        *(float4*)((char*)sH1 + (nr + 2) * 256 + ((fc * 4) ^ SWZ(nr + 2))) = r;
        r.x = fmaxf(acc30, 0.f); r.y = fmaxf(acc31, 0.f); r.z = fmaxf(acc32, 0.f); r.w = fmaxf(acc33, 0.f);
        *(float4*)((char*)sH1 + (nr + 3) * 256 + ((fc * 4) ^ SWZ(nr + 3))) = r;
    }

    __syncthreads();
#pragma unroll
    for (int it = 0; it < 4; ++it) ((float4*)sW)[it * 256 + tid] = W2_4[it * 256 + tid];
    __syncthreads();

    bias = ((const float4*)b2)[tid & 15];
    acc00 = bias.x; acc01 = bias.y; acc02 = bias.z; acc03 = bias.w;
    acc10 = bias.x; acc11 = bias.y; acc12 = bias.z; acc13 = bias.w;
    acc20 = bias.x; acc21 = bias.y; acc22 = bias.z; acc23 = bias.w;
    acc30 = bias.x; acc31 = bias.y; acc32 = bias.z; acc33 = bias.w;

    GEMM_LOOP(sH1)

    float sj0 = 0.f, sj1 = 0.f, sj2 = 0.f, sj3 = 0.f;
    float qj0 = 0.f, qj1 = 0.f, qj2 = 0.f, qj3 = 0.f;
    {
        int node = n0 + nr;
        float4 r;
        if (node + 0 < nNodes) {
            r.x = fmaxf(acc00, 0.f); r.y = fmaxf(acc01, 0.f); r.z = fmaxf(acc02, 0.f); r.w = fmaxf(acc03, 0.f);
            h_out4[(size_t)(node + 0) * 16 + (fc >> 2)] = r;
            sj0 += r.x; qj0 += r.x * r.x; sj1 += r.y; qj1 += r.y * r.y;
            sj2 += r.z; qj2 += r.z * r.z; sj3 += r.w; qj3 += r.w * r.w;
        }
        if (node + 1 < nNodes) {
            r.x = fmaxf(acc10, 0.f); r.y = fmaxf(acc11, 0.f); r.z = fmaxf(acc12, 0.f); r.w = fmaxf(acc13, 0.f);
            h_out4[(size_t)(node + 1) * 16 + (fc >> 2)] = r;
            sj0 += r.x; qj0 += r.x * r.x; sj1 += r.y; qj1 += r.y * r.y;
            sj2 += r.z; qj2 += r.z * r.z; sj3 += r.w; qj3 += r.w * r.w;
        }
        if (node + 2 < nNodes) {
            r.x = fmaxf(acc20, 0.f); r.y = fmaxf(acc21, 0.f); r.z = fmaxf(acc22, 0.f); r.w = fmaxf(acc23, 0.f);
            h_out4[(size_t)(node + 2) * 16 + (fc >> 2)] = r;
            sj0 += r.x; qj0 += r.x * r.x; sj1 += r.y; qj1 += r.y * r.y;
            sj2 += r.z; qj2 += r.z * r.z; sj3 += r.w; qj3 += r.w * r.w;
        }
        if (node + 3 < nNodes) {
            r.x = fmaxf(acc30, 0.f); r.y = fmaxf(acc31, 0.f); r.z = fmaxf(acc32, 0.f); r.w = fmaxf(acc33, 0.f);
            h_out4[(size_t)(node + 3) * 16 + (fc >> 2)] = r;
            sj0 += r.x; qj0 += r.x * r.x; sj1 += r.y; qj1 += r.y * r.y;
            sj2 += r.z; qj2 += r.z * r.z; sj3 += r.w; qj3 += r.w * r.w;
        }
    }

    float* sS = sA;
    float* sQ = sA + 1024;
    __syncthreads();
    int rrow = tid >> 4;
    sS[rrow * 64 + fc + 0] = sj0; sS[rrow * 64 + fc + 1] = sj1;
    sS[rrow * 64 + fc + 2] = sj2; sS[rrow * 64 + fc + 3] = sj3;
    sQ[rrow * 64 + fc + 0] = qj0; sQ[rrow * 64 + fc + 1] = qj1;
    sQ[rrow * 64 + fc + 2] = qj2; sQ[rrow * 64 + fc + 3] = qj3;
    __syncthreads();
    if (tid < 64) {
        float S = 0.f;
#pragma unroll
        for (int r = 0; r < 16; ++r) S += sS[r * 64 + tid];
        atomicAdd(&statsO[tid], S);
    } else if (tid < 128) {
        int f = tid - 64;
        float Q = 0.f;
#pragma unroll
        for (int r = 0; r < 16; ++r) Q += sQ[r * 64 + f];
        atomicAdd(&statsO[64 + f], Q);
    }
}

// ---------------- pooling (BN3 fused) + final GEMV ----------------
__device__ __forceinline__ int lower_bound_dev(const int* a, int n, int key) {
    int lo = 0, hi = n;
    while (lo < hi) {
        int mid = (lo + hi) >> 1;
        if (a[mid] < key) lo = mid + 1; else hi = mid;
    }
    return lo;
}

__global__ __launch_bounds__(256) void k_pool(const float4* __restrict__ x4,
                                              const int* __restrict__ batch,
                                              const float* __restrict__ stats,
                                              const float* __restrict__ gamma,
                                              const float* __restrict__ beta,
                                              const float* __restrict__ Wf,
                                              const float* __restrict__ bf,
                                              float* __restrict__ out,
                                              int nNodes, float invN) {
    int wid = threadIdx.x >> 6;
    int lane = threadIdx.x & 63;
    int grp = lane >> 4;
    int l16 = lane & 15;
    int g = blockIdx.x * 4 + wid;

    float4 sc, sh;
    {
        float4 s  = ((const float4*)stats)[l16];
        float4 q  = ((const float4*)stats)[16 + l16];
        float4 ga = ((const float4*)gamma)[l16];
        float4 be = ((const float4*)beta)[l16];
        float m;
        m = s.x * invN; sc.x = ga.x * rsqrtf(q.x * invN - m * m + 1e-5f); sh.x = be.x - m * sc.x;
        m = s.y * invN; sc.y = ga.y * rsqrtf(q.y * invN - m * m + 1e-5f); sh.y = be.y - m * sc.y;
        m = s.z * invN; sc.z = ga.z * rsqrtf(q.z * invN - m * m + 1e-5f); sh.z = be.z - m * sc.z;
        m = s.w * invN; sc.w = ga.w * rsqrtf(q.w * invN - m * m + 1e-5f); sh.w = be.w - m * sc.w;
    }

    int lo = lower_bound_dev(batch, nNodes, g);
    int hi = lower_bound_dev(batch, nNodes, g + 1);

    float4 acc = f4zero();
    for (int r = lo + grp; r < hi; r += 4) {
        float4 v = x4[(size_t)r * 16 + l16];
        acc.x += fmaxf(fmaf(v.x, sc.x, sh.x), 0.f);
        acc.y += fmaxf(fmaf(v.y, sc.y, sh.y), 0.f);
        acc.z += fmaxf(fmaf(v.z, sc.z, sh.z), 0.f);
        acc.w += fmaxf(fmaf(v.w, sc.w, sh.w), 0.f);
    }
    acc.x += __shfl_xor(acc.x, 16, 64); acc.y += __shfl_xor(acc.y, 16, 64);
    acc.z += __shfl_xor(acc.z, 16, 64); acc.w += __shfl_xor(acc.w, 16, 64);
    acc.x += __shfl_xor(acc.x, 32, 64); acc.y += __shfl_xor(acc.y, 32, 64);
    acc.z += __shfl_xor(acc.z, 32, 64); acc.w += __shfl_xor(acc.w, 32, 64);

    float4 wf = ((const float4*)Wf)[l16];
    float p = acc.x * wf.x + acc.y * wf.y + acc.z * wf.z + acc.w * wf.w;
    p += __shfl_xor(p, 1, 64);
    p += __shfl_xor(p, 2, 64);
    p += __shfl_xor(p, 4, 64);
    p += __shfl_xor(p, 8, 64);
    if (lane == 0) out[g] = p + bf[0];
}

extern "C" void kernel_launch(void* const* d_in, const int* in_sizes, int n_in,
                              void* d_out, int out_size, void* d_ws, size_t ws_size,
                              hipStream_t stream) {
    const float* x_in  = (const float*)d_in[0];
    const int*   ei    = (const int*)d_in[1];
    const int*   batch = (const int*)d_in[2];
    const float* W1    = (const float*)d_in[3];
    const float* b1    = (const float*)d_in[4];
    const float* W2    = (const float*)d_in[5];
    const float* b2    = (const float*)d_in[6];
    const float* gamma = (const float*)d_in[7];
    const float* beta  = (const float*)d_in[8];
    const float* Wf    = (const float*)d_in[9];
    const float* bf    = (const float*)d_in[10];

    const int nNodes = in_sizes[0] / HIDDEN_C;   // 50000 (pack assumes <= 65536)
    const int nE = in_sizes[1] / 2;              // 800000
    const int* src = ei;
    const int* dst = ei + nE;

    const int nBuckets = (nNodes + 63) / 64;     // 782
    const int nTot = nBuckets * NCHUNK;          // 50048
    const int chunkSz = (nE + NCHUNK - 1) / NCHUNK;
    const int scanBlocks = (nTot + 1023) / 1024; // 49
    const float invN = 1.f / (float)nNodes;

    const size_t NB = (size_t)nNodes * HIDDEN_C * sizeof(float);  // 12.8 MB
    char* ws = (char*)d_ws;
    float*    bufA    = (float*)ws;
    float*    bufB    = (float*)(ws + NB);
    float*    stats   = (float*)(ws + 2 * NB);            // 3 x 128 floats (4KB pad)
    int*      rowptr  = (int*)(ws + 2 * NB + 4096);       // nNodes+1
    int*      partial = rowptr + nNodes + 64;             // 256
    int*      col     = partial + 256;                    // nE
    // transient CSR-build scratch aliased into bufB (bufB first written by layer 1)
    unsigned* ebuf    = (unsigned*)bufB;                  // nE
    int*      cnt     = (int*)(bufB + nE);                // nTot
    int*      eoff    = cnt + nTot + 64;                  // nTot

    hipMemsetAsync(stats, 0, 384 * sizeof(float), stream);

    // ---- CSR build via 64-node buckets ----
    k_bcount<<<NCHUNK, 256, 0, stream>>>(dst, cnt, nE, chunkSz, nBuckets);
    k_blocksum<<<scanBlocks, 256, 0, stream>>>(cnt, partial, nTot);
    k_scanpartial<<<1, 256, 0, stream>>>(partial, rowptr + nNodes, scanBlocks, nE);
    k_writeptr<<<scanBlocks, 256, 0, stream>>>(cnt, partial, eoff, eoff, nTot);
    k_bscatter<<<NCHUNK, 256, 0, stream>>>(src, dst, eoff, ebuf, nE, chunkSz, nBuckets);
    k_bfill<<<nBuckets, 256, 0, stream>>>(ebuf, eoff, rowptr, col, nNodes, nE, nBuckets);

    // ---- 3 fused layers ----
    const float* prev_h = x_in;
    float* cur = bufA;
    for (int i = 0; i < 3; ++i) {
        if (i == 0) {
            k_layer<false><<<nBuckets, 256, 0, stream>>>(prev_h, rowptr, col,
                (const float4*)(W1), b1,
                (const float4*)(W2), b2,
                nullptr, nullptr, nullptr,
                stats, (float4*)cur, nNodes, invN);
        } else {
            k_layer<true><<<nBuckets, 256, 0, stream>>>(prev_h, rowptr, col,
                (const float4*)(W1 + (size_t)i * 4096), b1 + (size_t)i * 64,
                (const float4*)(W2 + (size_t)i * 4096), b2 + (size_t)i * 64,
                stats + (size_t)(i - 1) * 128, gamma + (size_t)(i - 1) * 64, beta + (size_t)(i - 1) * 64,
                stats + (size_t)i * 128, (float4*)cur, nNodes, invN);
        }
        prev_h = cur;
        cur = (cur == bufA) ? bufB : bufA;
    }

    k_pool<<<64, 256, 0, stream>>>((const float4*)prev_h, batch,
                                   stats + 256, gamma + 128, beta + 128,
                                   Wf, bf, (float*)d_out, nNodes, invN);
}

// Round 7
// 286.797 us; speedup vs baseline: 1.4406x; 1.4406x over previous
//
#include <hip/hip_runtime.h>

#define HIDDEN_C 64
#define NCHUNK 64

__device__ __forceinline__ float4 f4zero() { return make_float4(0.f, 0.f, 0.f, 0.f); }

#define SWZ(node) ((((node) >> 2) & 7) << 4)

// ---------------- generic exclusive scan ----------------
__global__ __launch_bounds__(256) void k_blocksum(const int* __restrict__ deg,
                                                  int* __restrict__ partial, int n) {
    int base = blockIdx.x * 1024 + threadIdx.x * 4;
    int s = 0;
#pragma unroll
    for (int k = 0; k < 4; ++k) {
        int i = base + k;
        if (i < n) s += deg[i];
    }
    __shared__ int red[256];
    red[threadIdx.x] = s;
    __syncthreads();
    for (int d = 128; d > 0; d >>= 1) {
        if (threadIdx.x < d) red[threadIdx.x] += red[threadIdx.x + d];
        __syncthreads();
    }
    if (threadIdx.x == 0) partial[blockIdx.x] = red[0];
}

__global__ __launch_bounds__(256) void k_scanpartial(int* __restrict__ partial,
                                                     int* __restrict__ last_slot,
                                                     int nBlocks, int nE) {
    __shared__ int buf[256];
    int tid = threadIdx.x;
    int v = (tid < nBlocks) ? partial[tid] : 0;
    buf[tid] = v;
    __syncthreads();
    for (int d = 1; d < 256; d <<= 1) {
        int t = (tid >= d) ? buf[tid - d] : 0;
        __syncthreads();
        buf[tid] += t;
        __syncthreads();
    }
    if (tid < nBlocks) partial[tid] = buf[tid] - v;
    if (tid == 0) last_slot[0] = nE;
}

__global__ __launch_bounds__(256) void k_writeptr(const int* __restrict__ deg,
                                                  const int* __restrict__ partial,
                                                  int* __restrict__ outp,
                                                  int* __restrict__ outp2, int n) {
    int tid = threadIdx.x;
    int base = blockIdx.x * 1024 + tid * 4;
    int d[4];
    int s = 0;
#pragma unroll
    for (int k = 0; k < 4; ++k) {
        int i = base + k;
        d[k] = (i < n) ? deg[i] : 0;
        s += d[k];
    }
    __shared__ int buf[256];
    buf[tid] = s;
    __syncthreads();
    for (int dd = 1; dd < 256; dd <<= 1) {
        int t = (tid >= dd) ? buf[tid - dd] : 0;
        __syncthreads();
        buf[tid] += t;
        __syncthreads();
    }
    int off = partial[blockIdx.x] + buf[tid] - s;
#pragma unroll
    for (int k = 0; k < 4; ++k) {
        int i = base + k;
        if (i < n) {
            outp[i] = off;
            outp2[i] = off;
            off += d[k];
        }
    }
}

// ---------------- bucket partition (bucket = dst>>6) ----------------
__global__ __launch_bounds__(256) void k_bcount(const int* __restrict__ dst,
                                                int* __restrict__ cnt,
                                                int nE, int chunkSz, int nBuckets) {
    __shared__ int h[1024];
    int c = blockIdx.x, tid = threadIdx.x;
    for (int i = tid; i < nBuckets; i += 256) h[i] = 0;
    __syncthreads();
    int beg = c * chunkSz;
    int end = beg + chunkSz; if (end > nE) end = nE;
    for (int e = beg + tid; e < end; e += 256) atomicAdd(&h[dst[e] >> 6], 1);
    __syncthreads();
    for (int i = tid; i < nBuckets; i += 256) cnt[i * NCHUNK + c] = h[i];
}

__global__ __launch_bounds__(256) void k_bscatter(const int* __restrict__ src,
                                                  const int* __restrict__ dst,
                                                  const int* __restrict__ eoff,
                                                  unsigned* __restrict__ ebuf,
                                                  int nE, int chunkSz, int nBuckets) {
    __shared__ int cur[1024];
    int c = blockIdx.x, tid = threadIdx.x;
    for (int i = tid; i < nBuckets; i += 256) cur[i] = eoff[i * NCHUNK + c];
    __syncthreads();
    int beg = c * chunkSz;
    int end = beg + chunkSz; if (end > nE) end = nE;
    for (int e = beg + tid; e < end; e += 256) {
        int d = dst[e];
        int b = d >> 6;
        int pos = atomicAdd(&cur[b], 1);
        ebuf[pos] = ((unsigned)(d & 63) << 16) | (unsigned)src[e];  // nNodes<=65536
    }
}

__global__ __launch_bounds__(256) void k_bfill(const unsigned* __restrict__ ebuf,
                                               const int* __restrict__ eoff,
                                               int* __restrict__ rowptr,
                                               int* __restrict__ col,
                                               int nNodes, int nE, int nBuckets) {
    __shared__ int deg[64], cur[64];
    int b = blockIdx.x, tid = threadIdx.x;
    int lo = eoff[b * NCHUNK];
    int hi = (b + 1 < nBuckets) ? eoff[(b + 1) * NCHUNK] : nE;
    if (tid < 64) deg[tid] = 0;
    __syncthreads();
    for (int e = lo + tid; e < hi; e += 256) atomicAdd(&deg[ebuf[e] >> 16], 1);
    __syncthreads();
    if (tid < 64) {
        int d = deg[tid];
        int s = d;
        for (int o = 1; o < 64; o <<= 1) {
            int t = __shfl_up(s, o, 64);
            if (tid >= o) s += t;
        }
        int st = s - d;
        cur[tid] = lo + st;
        int node = b * 64 + tid;
        if (node < nNodes) rowptr[node] = lo + st;
    }
    __syncthreads();
    for (int e = lo + tid; e < hi; e += 256) {
        unsigned pk = ebuf[e];
        int pos = atomicAdd(&cur[pk >> 16], 1);
        col[pos] = (int)(pk & 0xFFFFu);
    }
}

// ---------------- fused BN(prev layer) + gather aggregation ----------------
// wave = 1 node; 4 lane-groups x 16 lanes (float4); main loop 8 edges/iter unmasked
template <bool DOBN>
__global__ __launch_bounds__(256) void k_aggbn(const float4* __restrict__ x4,
                                               const int* __restrict__ rowptr,
                                               const int* __restrict__ col,
                                               const float* __restrict__ stats,
                                               const float* __restrict__ gamma,
                                               const float* __restrict__ beta,
                                               float4* __restrict__ h4,
                                               int nNodes, float invN) {
    int wid = threadIdx.x >> 6;
    int lane = threadIdx.x & 63;
    int grp = lane >> 4;
    int l16 = lane & 15;
    int n = blockIdx.x * 4 + wid;
    if (n >= nNodes) return;

    float4 sc = make_float4(1.f, 1.f, 1.f, 1.f);
    float4 sh = f4zero();
    if (DOBN) {
        float4 s  = ((const float4*)stats)[l16];
        float4 q  = ((const float4*)stats)[16 + l16];
        float4 ga = ((const float4*)gamma)[l16];
        float4 be = ((const float4*)beta)[l16];
        float m;
        m = s.x * invN; sc.x = ga.x * rsqrtf(q.x * invN - m * m + 1e-5f); sh.x = be.x - m * sc.x;
        m = s.y * invN; sc.y = ga.y * rsqrtf(q.y * invN - m * m + 1e-5f); sh.y = be.y - m * sc.y;
        m = s.z * invN; sc.z = ga.z * rsqrtf(q.z * invN - m * m + 1e-5f); sh.z = be.z - m * sc.z;
        m = s.w * invN; sc.w = ga.w * rsqrtf(q.w * invN - m * m + 1e-5f); sh.w = be.w - m * sc.w;
    }

    float4 acc = f4zero();
    {
        float4 v = x4[(size_t)n * 16 + l16];
        if (DOBN) {
            v.x = fmaxf(fmaf(v.x, sc.x, sh.x), 0.f);
            v.y = fmaxf(fmaf(v.y, sc.y, sh.y), 0.f);
            v.z = fmaxf(fmaf(v.z, sc.z, sh.z), 0.f);
            v.w = fmaxf(fmaf(v.w, sc.w, sh.w), 0.f);
        }
        if (grp == 0) acc = v;
    }

    int lo = rowptr[n], hi = rowptr[n + 1];
    int e = lo;
    for (; e + 8 <= hi; e += 8) {
        int i0 = col[e + grp];
        int i1 = col[e + 4 + grp];
        float4 v0 = x4[(size_t)i0 * 16 + l16];
        float4 v1 = x4[(size_t)i1 * 16 + l16];
        if (DOBN) {
            v0.x = fmaxf(fmaf(v0.x, sc.x, sh.x), 0.f);
            v0.y = fmaxf(fmaf(v0.y, sc.y, sh.y), 0.f);
            v0.z = fmaxf(fmaf(v0.z, sc.z, sh.z), 0.f);
            v0.w = fmaxf(fmaf(v0.w, sc.w, sh.w), 0.f);
            v1.x = fmaxf(fmaf(v1.x, sc.x, sh.x), 0.f);
            v1.y = fmaxf(fmaf(v1.y, sc.y, sh.y), 0.f);
            v1.z = fmaxf(fmaf(v1.z, sc.z, sh.z), 0.f);
            v1.w = fmaxf(fmaf(v1.w, sc.w, sh.w), 0.f);
        }
        acc.x += v0.x + v1.x; acc.y += v0.y + v1.y;
        acc.z += v0.z + v1.z; acc.w += v0.w + v1.w;
    }
    for (; e < hi; e += 4) {
        int ee = e + grp;
        bool ok = ee < hi;
        int idx = col[ok ? ee : (hi - 1)];
        float4 v = x4[(size_t)idx * 16 + l16];
        if (DOBN) {
            v.x = fmaxf(fmaf(v.x, sc.x, sh.x), 0.f);
            v.y = fmaxf(fmaf(v.y, sc.y, sh.y), 0.f);
            v.z = fmaxf(fmaf(v.z, sc.z, sh.z), 0.f);
            v.w = fmaxf(fmaf(v.w, sc.w, sh.w), 0.f);
        }
        if (ok) {
            acc.x += v.x; acc.y += v.y; acc.z += v.z; acc.w += v.w;
        }
    }

    acc.x += __shfl_xor(acc.x, 16, 64); acc.y += __shfl_xor(acc.y, 16, 64);
    acc.z += __shfl_xor(acc.z, 16, 64); acc.w += __shfl_xor(acc.w, 16, 64);
    acc.x += __shfl_xor(acc.x, 32, 64); acc.y += __shfl_xor(acc.y, 32, 64);
    acc.z += __shfl_xor(acc.z, 32, 64); acc.w += __shfl_xor(acc.w, 32, 64);

    if (lane < 16) h4[(size_t)n * 16 + l16] = acc;
}

// ---------------- fused 2-layer MLP + BN-stats (b128 LDS, swizzled) ----------------
#define KSTEP(AC, WV)                                                       \
    acc00 = fmaf(a0.AC, WV.x, acc00); acc01 = fmaf(a0.AC, WV.y, acc01);     \
    acc02 = fmaf(a0.AC, WV.z, acc02); acc03 = fmaf(a0.AC, WV.w, acc03);     \
    acc10 = fmaf(a1.AC, WV.x, acc10); acc11 = fmaf(a1.AC, WV.y, acc11);     \
    acc12 = fmaf(a1.AC, WV.z, acc12); acc13 = fmaf(a1.AC, WV.w, acc13);     \
    acc20 = fmaf(a2.AC, WV.x, acc20); acc21 = fmaf(a2.AC, WV.y, acc21);     \
    acc22 = fmaf(a2.AC, WV.z, acc22); acc23 = fmaf(a2.AC, WV.w, acc23);     \
    acc30 = fmaf(a3.AC, WV.x, acc30); acc31 = fmaf(a3.AC, WV.y, acc31);     \
    acc32 = fmaf(a3.AC, WV.z, acc32); acc33 = fmaf(a3.AC, WV.w, acc33);

// unroll 4 (not 16): limits in-flight b128 loads; full unroll hit 256 VGPR / 8.5% occ
#define GEMM_LOOP(SRC)                                                                     \
    _Pragma("unroll 4")                                                                    \
    for (int kb = 0; kb < 16; ++kb) {                                                      \
        int kB = kb * 16;                                                                  \
        float4 a0 = *(const float4*)((const char*)SRC + (nr + 0) * 256 + (kB ^ SWZ(nr + 0))); \
        float4 a1 = *(const float4*)((const char*)SRC + (nr + 1) * 256 + (kB ^ SWZ(nr + 1))); \
        float4 a2 = *(const float4*)((const char*)SRC + (nr + 2) * 256 + (kB ^ SWZ(nr + 2))); \
        float4 a3 = *(const float4*)((const char*)SRC + (nr + 3) * 256 + (kB ^ SWZ(nr + 3))); \
        const char* wrow = (const char*)sW + kb * 1024 + fc * 4;                           \
        float4 w0 = *(const float4*)(wrow);                                               \
        float4 w1 = *(const float4*)(wrow + 256);                                         \
        float4 w2 = *(const float4*)(wrow + 512);                                         \
        float4 w3 = *(const float4*)(wrow + 768);                                         \
        KSTEP(x, w0) KSTEP(y, w1) KSTEP(z, w2) KSTEP(w, w3)                                \
    }

__global__ __launch_bounds__(256, 4) void k_mlp(const float4* __restrict__ h_in4,
                                                float4* __restrict__ h_out4,
                                                const float4* __restrict__ W1_4,
                                                const float* __restrict__ b1,
                                                const float4* __restrict__ W2_4,
                                                const float* __restrict__ b2,
                                                float* __restrict__ stats,
                                                int nNodes) {
    __shared__ float sA[4096];
    __shared__ float sW[4096];
    __shared__ float sH1[4096];

    int tid = threadIdx.x;
    int n0 = blockIdx.x * 64;
    int nr = (tid >> 4) * 4;
    int fc = (tid & 15) * 4;

#pragma unroll
    for (int it = 0; it < 4; ++it) {
        int i = it * 256 + tid;
        ((float4*)sW)[i] = W1_4[i];
        int node = i >> 4, slot = i & 15;
        float4 v = (n0 + node < nNodes) ? h_in4[(size_t)(n0 + node) * 16 + slot] : f4zero();
        *(float4*)((char*)sA + node * 256 + ((slot * 16) ^ SWZ(node))) = v;
    }
    __syncthreads();

    float4 bias = ((const float4*)b1)[tid & 15];
    float acc00 = bias.x, acc01 = bias.y, acc02 = bias.z, acc03 = bias.w;
    float acc10 = bias.x, acc11 = bias.y, acc12 = bias.z, acc13 = bias.w;
    float acc20 = bias.x, acc21 = bias.y, acc22 = bias.z, acc23 = bias.w;
    float acc30 = bias.x, acc31 = bias.y, acc32 = bias.z, acc33 = bias.w;

    GEMM_LOOP(sA)

    {
        float4 r;
        r.x = fmaxf(acc00, 0.f); r.y = fmaxf(acc01, 0.f); r.z = fmaxf(acc02, 0.f); r.w = fmaxf(acc03, 0.f);
        *(float4*)((char*)sH1 + (nr + 0) * 256 + ((fc * 4) ^ SWZ(nr + 0))) = r;
        r.x = fmaxf(acc10, 0.f); r.y = fmaxf(acc11, 0.f); r.z = fmaxf(acc12, 0.f); r.w = fmaxf(acc13, 0.f);
        *(float4*)((char*)sH1 + (nr + 1) * 256 + ((fc * 4) ^ SWZ(nr + 1))) = r;
        r.x = fmaxf(acc20, 0.f); r.y = fmaxf(acc21, 0.f); r.z = fmaxf(acc22, 0.f); r.w = fmaxf(acc23, 0.f);
        *(float4*)((char*)sH1 + (nr + 2) * 256 + ((fc * 4) ^ SWZ(nr + 2))) = r;
        r.x = fmaxf(acc30, 0.f); r.y = fmaxf(acc31, 0.f); r.z = fmaxf(acc32, 0.f); r.w = fmaxf(acc33, 0.f);
        *(float4*)((char*)sH1 + (nr + 3) * 256 + ((fc * 4) ^ SWZ(nr + 3))) = r;
    }

    __syncthreads();
#pragma unroll
    for (int it = 0; it < 4; ++it) {
        int i = it * 256 + tid;
        ((float4*)sW)[i] = W2_4[i];
    }
    __syncthreads();

    bias = ((const float4*)b2)[tid & 15];
    acc00 = bias.x; acc01 = bias.y; acc02 = bias.z; acc03 = bias.w;
    acc10 = bias.x; acc11 = bias.y; acc12 = bias.z; acc13 = bias.w;
    acc20 = bias.x; acc21 = bias.y; acc22 = bias.z; acc23 = bias.w;
    acc30 = bias.x; acc31 = bias.y; acc32 = bias.z; acc33 = bias.w;

    GEMM_LOOP(sH1)

    float sj0 = 0.f, sj1 = 0.f, sj2 = 0.f, sj3 = 0.f;
    float qj0 = 0.f, qj1 = 0.f, qj2 = 0.f, qj3 = 0.f;
    {
        int node = n0 + nr;
        float4 r;
        if (node + 0 < nNodes) {
            r.x = fmaxf(acc00, 0.f); r.y = fmaxf(acc01, 0.f); r.z = fmaxf(acc02, 0.f); r.w = fmaxf(acc03, 0.f);
            h_out4[(size_t)(node + 0) * 16 + (fc >> 2)] = r;
            sj0 += r.x; qj0 += r.x * r.x; sj1 += r.y; qj1 += r.y * r.y;
            sj2 += r.z; qj2 += r.z * r.z; sj3 += r.w; qj3 += r.w * r.w;
        }
        if (node + 1 < nNodes) {
            r.x = fmaxf(acc10, 0.f); r.y = fmaxf(acc11, 0.f); r.z = fmaxf(acc12, 0.f); r.w = fmaxf(acc13, 0.f);
            h_out4[(size_t)(node + 1) * 16 + (fc >> 2)] = r;
            sj0 += r.x; qj0 += r.x * r.x; sj1 += r.y; qj1 += r.y * r.y;
            sj2 += r.z; qj2 += r.z * r.z; sj3 += r.w; qj3 += r.w * r.w;
        }
        if (node + 2 < nNodes) {
            r.x = fmaxf(acc20, 0.f); r.y = fmaxf(acc21, 0.f); r.z = fmaxf(acc22, 0.f); r.w = fmaxf(acc23, 0.f);
            h_out4[(size_t)(node + 2) * 16 + (fc >> 2)] = r;
            sj0 += r.x; qj0 += r.x * r.x; sj1 += r.y; qj1 += r.y * r.y;
            sj2 += r.z; qj2 += r.z * r.z; sj3 += r.w; qj3 += r.w * r.w;
        }
        if (node + 3 < nNodes) {
            r.x = fmaxf(acc30, 0.f); r.y = fmaxf(acc31, 0.f); r.z = fmaxf(acc32, 0.f); r.w = fmaxf(acc33, 0.f);
            h_out4[(size_t)(node + 3) * 16 + (fc >> 2)] = r;
            sj0 += r.x; qj0 += r.x * r.x; sj1 += r.y; qj1 += r.y * r.y;
            sj2 += r.z; qj2 += r.z * r.z; sj3 += r.w; qj3 += r.w * r.w;
        }
    }

    float* sS = sA;
    float* sQ = sA + 1024;
    int rrow = tid >> 4;
    sS[rrow * 64 + fc + 0] = sj0; sS[rrow * 64 + fc + 1] = sj1;
    sS[rrow * 64 + fc + 2] = sj2; sS[rrow * 64 + fc + 3] = sj3;
    sQ[rrow * 64 + fc + 0] = qj0; sQ[rrow * 64 + fc + 1] = qj1;
    sQ[rrow * 64 + fc + 2] = qj2; sQ[rrow * 64 + fc + 3] = qj3;
    __syncthreads();
    if (tid < 64) {
        float S = 0.f;
#pragma unroll
        for (int r = 0; r < 16; ++r) S += sS[r * 64 + tid];
        atomicAdd(&stats[tid], S);
    } else if (tid < 128) {
        int f = tid - 64;
        float Q = 0.f;
#pragma unroll
        for (int r = 0; r < 16; ++r) Q += sQ[r * 64 + f];
        atomicAdd(&stats[64 + f], Q);
    }
}

// ---------------- pooling (BN3 fused) + final GEMV ----------------
__device__ __forceinline__ int lower_bound_dev(const int* a, int n, int key) {
    int lo = 0, hi = n;
    while (lo < hi) {
        int mid = (lo + hi) >> 1;
        if (a[mid] < key) lo = mid + 1; else hi = mid;
    }
    return lo;
}

__global__ __launch_bounds__(256) void k_pool(const float4* __restrict__ x4,
                                              const int* __restrict__ batch,
                                              const float* __restrict__ stats,
                                              const float* __restrict__ gamma,
                                              const float* __restrict__ beta,
                                              const float* __restrict__ Wf,
                                              const float* __restrict__ bf,
                                              float* __restrict__ out,
                                              int nNodes, float invN) {
    int wid = threadIdx.x >> 6;
    int lane = threadIdx.x & 63;
    int grp = lane >> 4;
    int l16 = lane & 15;
    int g = blockIdx.x * 4 + wid;

    float4 sc, sh;
    {
        float4 s  = ((const float4*)stats)[l16];
        float4 q  = ((const float4*)stats)[16 + l16];
        float4 ga = ((const float4*)gamma)[l16];
        float4 be = ((const float4*)beta)[l16];
        float m;
        m = s.x * invN; sc.x = ga.x * rsqrtf(q.x * invN - m * m + 1e-5f); sh.x = be.x - m * sc.x;
        m = s.y * invN; sc.y = ga.y * rsqrtf(q.y * invN - m * m + 1e-5f); sh.y = be.y - m * sc.y;
        m = s.z * invN; sc.z = ga.z * rsqrtf(q.z * invN - m * m + 1e-5f); sh.z = be.z - m * sc.z;
        m = s.w * invN; sc.w = ga.w * rsqrtf(q.w * invN - m * m + 1e-5f); sh.w = be.w - m * sc.w;
    }

    int lo = lower_bound_dev(batch, nNodes, g);
    int hi = lower_bound_dev(batch, nNodes, g + 1);

    float4 acc = f4zero();
    for (int r = lo + grp; r < hi; r += 4) {
        float4 v = x4[(size_t)r * 16 + l16];
        acc.x += fmaxf(fmaf(v.x, sc.x, sh.x), 0.f);
        acc.y += fmaxf(fmaf(v.y, sc.y, sh.y), 0.f);
        acc.z += fmaxf(fmaf(v.z, sc.z, sh.z), 0.f);
        acc.w += fmaxf(fmaf(v.w, sc.w, sh.w), 0.f);
    }
    acc.x += __shfl_xor(acc.x, 16, 64); acc.y += __shfl_xor(acc.y, 16, 64);
    acc.z += __shfl_xor(acc.z, 16, 64); acc.w += __shfl_xor(acc.w, 16, 64);
    acc.x += __shfl_xor(acc.x, 32, 64); acc.y += __shfl_xor(acc.y, 32, 64);
    acc.z += __shfl_xor(acc.z, 32, 64); acc.w += __shfl_xor(acc.w, 32, 64);

    float4 wf = ((const float4*)Wf)[l16];
    float p = acc.x * wf.x + acc.y * wf.y + acc.z * wf.z + acc.w * wf.w;
    p += __shfl_xor(p, 1, 64);
    p += __shfl_xor(p, 2, 64);
    p += __shfl_xor(p, 4, 64);
    p += __shfl_xor(p, 8, 64);
    if (lane == 0) out[g] = p + bf[0];
}

extern "C" void kernel_launch(void* const* d_in, const int* in_sizes, int n_in,
                              void* d_out, int out_size, void* d_ws, size_t ws_size,
                              hipStream_t stream) {
    const float* x_in  = (const float*)d_in[0];
    const int*   ei    = (const int*)d_in[1];
    const int*   batch = (const int*)d_in[2];
    const float* W1    = (const float*)d_in[3];
    const float* b1    = (const float*)d_in[4];
    const float* W2    = (const float*)d_in[5];
    const float* b2    = (const float*)d_in[6];
    const float* gamma = (const float*)d_in[7];
    const float* beta  = (const float*)d_in[8];
    const float* Wf    = (const float*)d_in[9];
    const float* bf    = (const float*)d_in[10];

    const int nNodes = in_sizes[0] / HIDDEN_C;   // 50000 (pack assumes <= 65536)
    const int nE = in_sizes[1] / 2;              // 800000
    const int* src = ei;
    const int* dst = ei + nE;

    const int nBuckets = (nNodes + 63) / 64;     // 782
    const int nTot = nBuckets * NCHUNK;          // 50048
    const int chunkSz = (nE + NCHUNK - 1) / NCHUNK;
    const int scanBlocks = (nTot + 1023) / 1024; // 49
    const float invN = 1.f / (float)nNodes;

    const size_t NB = (size_t)nNodes * HIDDEN_C * sizeof(float);  // 12.8 MB
    char* ws = (char*)d_ws;
    float*    bufA    = (float*)ws;
    float*    bufB    = (float*)(ws + NB);
    float*    stats   = (float*)(ws + 2 * NB);            // 3 x 128 floats
    int*      rowptr  = (int*)(ws + 2 * NB + 4096);       // nNodes+1
    int*      partial = rowptr + nNodes + 64;             // 256
    int*      col     = partial + 256;                    // nE
    // transient CSR-build scratch aliased into bufB (bufB first written at layer 1)
    unsigned* ebuf    = (unsigned*)bufB;                  // nE
    int*      cnt     = (int*)(bufB + nE);                // nTot
    int*      eoff    = cnt + nTot + 64;                  // nTot

    const int mlpGrid = (nNodes + 63) / 64;
    const int aggGrid = (nNodes + 3) / 4;

    hipMemsetAsync(stats, 0, 384 * sizeof(float), stream);

    // ---- CSR build via 64-node buckets (line-friendly writes) ----
    k_bcount<<<NCHUNK, 256, 0, stream>>>(dst, cnt, nE, chunkSz, nBuckets);
    k_blocksum<<<scanBlocks, 256, 0, stream>>>(cnt, partial, nTot);
    k_scanpartial<<<1, 256, 0, stream>>>(partial, rowptr + nNodes, scanBlocks, nE);
    k_writeptr<<<scanBlocks, 256, 0, stream>>>(cnt, partial, eoff, eoff, nTot);
    k_bscatter<<<NCHUNK, 256, 0, stream>>>(src, dst, eoff, ebuf, nE, chunkSz, nBuckets);
    k_bfill<<<nBuckets, 256, 0, stream>>>(ebuf, eoff, rowptr, col, nNodes, nE, nBuckets);

    // ---- 3 layers: split agg (gather) + MLP ----
    const float* prev_h = x_in;
    float* cur = bufA;
    for (int i = 0; i < 3; ++i) {
        if (i == 0) {
            k_aggbn<false><<<aggGrid, 256, 0, stream>>>((const float4*)prev_h, rowptr, col,
                                                        nullptr, nullptr, nullptr,
                                                        (float4*)cur, nNodes, invN);
        } else {
            k_aggbn<true><<<aggGrid, 256, 0, stream>>>((const float4*)prev_h, rowptr, col,
                                                       stats + (size_t)(i - 1) * 128,
                                                       gamma + (size_t)(i - 1) * 64,
                                                       beta + (size_t)(i - 1) * 64,
                                                       (float4*)cur, nNodes, invN);
        }
        k_mlp<<<mlpGrid, 256, 0, stream>>>((const float4*)cur, (float4*)cur,
                                           (const float4*)(W1 + (size_t)i * 4096), b1 + (size_t)i * 64,
                                           (const float4*)(W2 + (size_t)i * 4096), b2 + (size_t)i * 64,
                                           stats + (size_t)i * 128, nNodes);
        prev_h = cur;
        cur = (cur == bufA) ? bufB : bufA;
    }

    k_pool<<<64, 256, 0, stream>>>((const float4*)prev_h, batch,
                                   stats + 256, gamma + 128, beta + 128,
                                   Wf, bf, (float*)d_out, nNodes, invN);
}

// Round 8
// 251.029 us; speedup vs baseline: 1.6459x; 1.1425x over previous
//
#include <hip/hip_runtime.h>

#define HIDDEN_C 64
#define NCHUNK 256

__device__ __forceinline__ float4 f4zero() { return make_float4(0.f, 0.f, 0.f, 0.f); }

#define SWZ(node) ((((node) >> 2) & 7) << 4)

// ---------------- generic exclusive scan ----------------
__global__ __launch_bounds__(256) void k_blocksum(const int* __restrict__ deg,
                                                  int* __restrict__ partial, int n) {
    int base = blockIdx.x * 1024 + threadIdx.x * 4;
    int s = 0;
#pragma unroll
    for (int k = 0; k < 4; ++k) {
        int i = base + k;
        if (i < n) s += deg[i];
    }
    __shared__ int red[256];
    red[threadIdx.x] = s;
    __syncthreads();
    for (int d = 128; d > 0; d >>= 1) {
        if (threadIdx.x < d) red[threadIdx.x] += red[threadIdx.x + d];
        __syncthreads();
    }
    if (threadIdx.x == 0) partial[blockIdx.x] = red[0];
}

__global__ __launch_bounds__(256) void k_scanpartial(int* __restrict__ partial,
                                                     int* __restrict__ last_slot,
                                                     int nBlocks, int nE) {
    __shared__ int buf[256];
    int tid = threadIdx.x;
    int v = (tid < nBlocks) ? partial[tid] : 0;
    buf[tid] = v;
    __syncthreads();
    for (int d = 1; d < 256; d <<= 1) {
        int t = (tid >= d) ? buf[tid - d] : 0;
        __syncthreads();
        buf[tid] += t;
        __syncthreads();
    }
    if (tid < nBlocks) partial[tid] = buf[tid] - v;
    if (tid == 0) last_slot[0] = nE;
}

__global__ __launch_bounds__(256) void k_writeptr(const int* __restrict__ deg,
                                                  const int* __restrict__ partial,
                                                  int* __restrict__ outp, int n) {
    int tid = threadIdx.x;
    int base = blockIdx.x * 1024 + tid * 4;
    int d[4];
    int s = 0;
#pragma unroll
    for (int k = 0; k < 4; ++k) {
        int i = base + k;
        d[k] = (i < n) ? deg[i] : 0;
        s += d[k];
    }
    __shared__ int buf[256];
    buf[tid] = s;
    __syncthreads();
    for (int dd = 1; dd < 256; dd <<= 1) {
        int t = (tid >= dd) ? buf[tid - dd] : 0;
        __syncthreads();
        buf[tid] += t;
        __syncthreads();
    }
    int off = partial[blockIdx.x] + buf[tid] - s;
#pragma unroll
    for (int k = 0; k < 4; ++k) {
        int i = base + k;
        if (i < n) {
            outp[i] = off;
            off += d[k];
        }
    }
}

// ---------------- bucket partition (bucket = dst>>6) ----------------
// also zeroes the 384-float stats array (block 0) so no hipMemsetAsync is needed
__global__ __launch_bounds__(256) void k_bcount(const int* __restrict__ dst,
                                                int* __restrict__ cnt,
                                                float* __restrict__ statsZ,
                                                int nE, int chunkSz, int nBuckets) {
    __shared__ int h[1024];
    int c = blockIdx.x, tid = threadIdx.x;
    if (c == 0) {
        for (int i = tid; i < 384; i += 256) statsZ[i] = 0.f;
    }
    for (int i = tid; i < nBuckets; i += 256) h[i] = 0;
    __syncthreads();
    int beg = c * chunkSz;
    int end = beg + chunkSz; if (end > nE) end = nE;
    int e = beg + tid;
    for (; e + 256 < end; e += 512) {
        int d0 = dst[e];
        int d1 = dst[e + 256];
        atomicAdd(&h[d0 >> 6], 1);
        atomicAdd(&h[d1 >> 6], 1);
    }
    if (e < end) atomicAdd(&h[dst[e] >> 6], 1);
    __syncthreads();
    for (int i = tid; i < nBuckets; i += 256) cnt[i * NCHUNK + c] = h[i];
}

__global__ __launch_bounds__(256) void k_bscatter(const int* __restrict__ src,
                                                  const int* __restrict__ dst,
                                                  const int* __restrict__ eoff,
                                                  unsigned* __restrict__ ebuf,
                                                  int nE, int chunkSz, int nBuckets) {
    __shared__ int cur[1024];
    int c = blockIdx.x, tid = threadIdx.x;
    for (int i = tid; i < nBuckets; i += 256) cur[i] = eoff[i * NCHUNK + c];
    __syncthreads();
    int beg = c * chunkSz;
    int end = beg + chunkSz; if (end > nE) end = nE;
    int e = beg + tid;
    for (; e + 256 < end; e += 512) {
        int d0 = dst[e];
        int d1 = dst[e + 256];
        int s0 = src[e];
        int s1 = src[e + 256];
        int p0 = atomicAdd(&cur[d0 >> 6], 1);
        int p1 = atomicAdd(&cur[d1 >> 6], 1);
        ebuf[p0] = ((unsigned)(d0 & 63) << 16) | (unsigned)s0;  // nNodes<=65536
        ebuf[p1] = ((unsigned)(d1 & 63) << 16) | (unsigned)s1;
    }
    if (e < end) {
        int d = dst[e];
        int pos = atomicAdd(&cur[d >> 6], 1);
        ebuf[pos] = ((unsigned)(d & 63) << 16) | (unsigned)src[e];
    }
}

__global__ __launch_bounds__(256) void k_bfill(const unsigned* __restrict__ ebuf,
                                               const int* __restrict__ eoff,
                                               int* __restrict__ rowptr,
                                               int* __restrict__ col,
                                               int nNodes, int nE, int nBuckets) {
    __shared__ int deg[64], cur[64];
    int b = blockIdx.x, tid = threadIdx.x;
    int lo = eoff[b * NCHUNK];
    int hi = (b + 1 < nBuckets) ? eoff[(b + 1) * NCHUNK] : nE;
    if (tid < 64) deg[tid] = 0;
    __syncthreads();
    for (int e = lo + tid; e < hi; e += 256) atomicAdd(&deg[ebuf[e] >> 16], 1);
    __syncthreads();
    if (tid < 64) {
        int d = deg[tid];
        int s = d;
        for (int o = 1; o < 64; o <<= 1) {
            int t = __shfl_up(s, o, 64);
            if (tid >= o) s += t;
        }
        int st = s - d;
        cur[tid] = lo + st;
        int node = b * 64 + tid;
        if (node < nNodes) rowptr[node] = lo + st;
    }
    __syncthreads();
    for (int e = lo + tid; e < hi; e += 256) {
        unsigned pk = ebuf[e];
        int pos = atomicAdd(&cur[pk >> 16], 1);
        col[pos] = (int)(pk & 0xFFFFu);
    }
}

// ---------------- fused BN(prev layer) + gather aggregation ----------------
// wave = 1 node; 4 lane-groups x 16 lanes (float4); main loop 8 edges/iter unmasked
template <bool DOBN>
__global__ __launch_bounds__(256) void k_aggbn(const float4* __restrict__ x4,
                                               const int* __restrict__ rowptr,
                                               const int* __restrict__ col,
                                               const float* __restrict__ stats,
                                               const float* __restrict__ gamma,
                                               const float* __restrict__ beta,
                                               float4* __restrict__ h4,
                                               int nNodes, float invN) {
    int wid = threadIdx.x >> 6;
    int lane = threadIdx.x & 63;
    int grp = lane >> 4;
    int l16 = lane & 15;
    int n = blockIdx.x * 4 + wid;
    if (n >= nNodes) return;

    float4 sc = make_float4(1.f, 1.f, 1.f, 1.f);
    float4 sh = f4zero();
    if (DOBN) {
        float4 s  = ((const float4*)stats)[l16];
        float4 q  = ((const float4*)stats)[16 + l16];
        float4 ga = ((const float4*)gamma)[l16];
        float4 be = ((const float4*)beta)[l16];
        float m;
        m = s.x * invN; sc.x = ga.x * rsqrtf(q.x * invN - m * m + 1e-5f); sh.x = be.x - m * sc.x;
        m = s.y * invN; sc.y = ga.y * rsqrtf(q.y * invN - m * m + 1e-5f); sh.y = be.y - m * sc.y;
        m = s.z * invN; sc.z = ga.z * rsqrtf(q.z * invN - m * m + 1e-5f); sh.z = be.z - m * sc.z;
        m = s.w * invN; sc.w = ga.w * rsqrtf(q.w * invN - m * m + 1e-5f); sh.w = be.w - m * sc.w;
    }

    float4 acc = f4zero();
    {
        float4 v = x4[(size_t)n * 16 + l16];
        if (DOBN) {
            v.x = fmaxf(fmaf(v.x, sc.x, sh.x), 0.f);
            v.y = fmaxf(fmaf(v.y, sc.y, sh.y), 0.f);
            v.z = fmaxf(fmaf(v.z, sc.z, sh.z), 0.f);
            v.w = fmaxf(fmaf(v.w, sc.w, sh.w), 0.f);
        }
        if (grp == 0) acc = v;
    }

    int lo = rowptr[n], hi = rowptr[n + 1];
    int e = lo;
    for (; e + 8 <= hi; e += 8) {
        int i0 = col[e + grp];
        int i1 = col[e + 4 + grp];
        float4 v0 = x4[(size_t)i0 * 16 + l16];
        float4 v1 = x4[(size_t)i1 * 16 + l16];
        if (DOBN) {
            v0.x = fmaxf(fmaf(v0.x, sc.x, sh.x), 0.f);
            v0.y = fmaxf(fmaf(v0.y, sc.y, sh.y), 0.f);
            v0.z = fmaxf(fmaf(v0.z, sc.z, sh.z), 0.f);
            v0.w = fmaxf(fmaf(v0.w, sc.w, sh.w), 0.f);
            v1.x = fmaxf(fmaf(v1.x, sc.x, sh.x), 0.f);
            v1.y = fmaxf(fmaf(v1.y, sc.y, sh.y), 0.f);
            v1.z = fmaxf(fmaf(v1.z, sc.z, sh.z), 0.f);
            v1.w = fmaxf(fmaf(v1.w, sc.w, sh.w), 0.f);
        }
        acc.x += v0.x + v1.x; acc.y += v0.y + v1.y;
        acc.z += v0.z + v1.z; acc.w += v0.w + v1.w;
    }
    for (; e < hi; e += 4) {
        int ee = e + grp;
        bool ok = ee < hi;
        int idx = col[ok ? ee : (hi - 1)];
        float4 v = x4[(size_t)idx * 16 + l16];
        if (DOBN) {
            v.x = fmaxf(fmaf(v.x, sc.x, sh.x), 0.f);
            v.y = fmaxf(fmaf(v.y, sc.y, sh.y), 0.f);
            v.z = fmaxf(fmaf(v.z, sc.z, sh.z), 0.f);
            v.w = fmaxf(fmaf(v.w, sc.w, sh.w), 0.f);
        }
        if (ok) {
            acc.x += v.x; acc.y += v.y; acc.z += v.z; acc.w += v.w;
        }
    }

    acc.x += __shfl_xor(acc.x, 16, 64); acc.y += __shfl_xor(acc.y, 16, 64);
    acc.z += __shfl_xor(acc.z, 16, 64); acc.w += __shfl_xor(acc.w, 16, 64);
    acc.x += __shfl_xor(acc.x, 32, 64); acc.y += __shfl_xor(acc.y, 32, 64);
    acc.z += __shfl_xor(acc.z, 32, 64); acc.w += __shfl_xor(acc.w, 32, 64);

    if (lane < 16) h4[(size_t)n * 16 + l16] = acc;
}

// ---------------- fused 2-layer MLP + BN-stats (b128 LDS, swizzled) ----------------
#define KSTEP(AC, WV)                                                       \
    acc00 = fmaf(a0.AC, WV.x, acc00); acc01 = fmaf(a0.AC, WV.y, acc01);     \
    acc02 = fmaf(a0.AC, WV.z, acc02); acc03 = fmaf(a0.AC, WV.w, acc03);     \
    acc10 = fmaf(a1.AC, WV.x, acc10); acc11 = fmaf(a1.AC, WV.y, acc11);     \
    acc12 = fmaf(a1.AC, WV.z, acc12); acc13 = fmaf(a1.AC, WV.w, acc13);     \
    acc20 = fmaf(a2.AC, WV.x, acc20); acc21 = fmaf(a2.AC, WV.y, acc21);     \
    acc22 = fmaf(a2.AC, WV.z, acc22); acc23 = fmaf(a2.AC, WV.w, acc23);     \
    acc30 = fmaf(a3.AC, WV.x, acc30); acc31 = fmaf(a3.AC, WV.y, acc31);     \
    acc32 = fmaf(a3.AC, WV.z, acc32); acc33 = fmaf(a3.AC, WV.w, acc33);

// unroll 4 (not 16): limits in-flight b128 loads; full unroll hit 256 VGPR / 8.5% occ
#define GEMM_LOOP(SRC)                                                                     \
    _Pragma("unroll 4")                                                                    \
    for (int kb = 0; kb < 16; ++kb) {                                                      \
        int kB = kb * 16;                                                                  \
        float4 a0 = *(const float4*)((const char*)SRC + (nr + 0) * 256 + (kB ^ SWZ(nr + 0))); \
        float4 a1 = *(const float4*)((const char*)SRC + (nr + 1) * 256 + (kB ^ SWZ(nr + 1))); \
        float4 a2 = *(const float4*)((const char*)SRC + (nr + 2) * 256 + (kB ^ SWZ(nr + 2))); \
        float4 a3 = *(const float4*)((const char*)SRC + (nr + 3) * 256 + (kB ^ SWZ(nr + 3))); \
        const char* wrow = (const char*)sW + kb * 1024 + fc * 4;                           \
        float4 w0 = *(const float4*)(wrow);                                               \
        float4 w1 = *(const float4*)(wrow + 256);                                         \
        float4 w2 = *(const float4*)(wrow + 512);                                         \
        float4 w3 = *(const float4*)(wrow + 768);                                         \
        KSTEP(x, w0) KSTEP(y, w1) KSTEP(z, w2) KSTEP(w, w3)                                \
    }

__global__ __launch_bounds__(256, 4) void k_mlp(const float4* __restrict__ h_in4,
                                                float4* __restrict__ h_out4,
                                                const float4* __restrict__ W1_4,
                                                const float* __restrict__ b1,
                                                const float4* __restrict__ W2_4,
                                                const float* __restrict__ b2,
                                                float* __restrict__ stats,
                                                int nNodes) {
    __shared__ float sA[4096];
    __shared__ float sW[4096];
    __shared__ float sH1[4096];

    int tid = threadIdx.x;
    int n0 = blockIdx.x * 64;
    int nr = (tid >> 4) * 4;
    int fc = (tid & 15) * 4;

#pragma unroll
    for (int it = 0; it < 4; ++it) {
        int i = it * 256 + tid;
        ((float4*)sW)[i] = W1_4[i];
        int node = i >> 4, slot = i & 15;
        float4 v = (n0 + node < nNodes) ? h_in4[(size_t)(n0 + node) * 16 + slot] : f4zero();
        *(float4*)((char*)sA + node * 256 + ((slot * 16) ^ SWZ(node))) = v;
    }
    __syncthreads();

    float4 bias = ((const float4*)b1)[tid & 15];
    float acc00 = bias.x, acc01 = bias.y, acc02 = bias.z, acc03 = bias.w;
    float acc10 = bias.x, acc11 = bias.y, acc12 = bias.z, acc13 = bias.w;
    float acc20 = bias.x, acc21 = bias.y, acc22 = bias.z, acc23 = bias.w;
    float acc30 = bias.x, acc31 = bias.y, acc32 = bias.z, acc33 = bias.w;

    GEMM_LOOP(sA)

    {
        float4 r;
        r.x = fmaxf(acc00, 0.f); r.y = fmaxf(acc01, 0.f); r.z = fmaxf(acc02, 0.f); r.w = fmaxf(acc03, 0.f);
        *(float4*)((char*)sH1 + (nr + 0) * 256 + ((fc * 4) ^ SWZ(nr + 0))) = r;
        r.x = fmaxf(acc10, 0.f); r.y = fmaxf(acc11, 0.f); r.z = fmaxf(acc12, 0.f); r.w = fmaxf(acc13, 0.f);
        *(float4*)((char*)sH1 + (nr + 1) * 256 + ((fc * 4) ^ SWZ(nr + 1))) = r;
        r.x = fmaxf(acc20, 0.f); r.y = fmaxf(acc21, 0.f); r.z = fmaxf(acc22, 0.f); r.w = fmaxf(acc23, 0.f);
        *(float4*)((char*)sH1 + (nr + 2) * 256 + ((fc * 4) ^ SWZ(nr + 2))) = r;
        r.x = fmaxf(acc30, 0.f); r.y = fmaxf(acc31, 0.f); r.z = fmaxf(acc32, 0.f); r.w = fmaxf(acc33, 0.f);
        *(float4*)((char*)sH1 + (nr + 3) * 256 + ((fc * 4) ^ SWZ(nr + 3))) = r;
    }

    __syncthreads();
#pragma unroll
    for (int it = 0; it < 4; ++it) {
        int i = it * 256 + tid;
        ((float4*)sW)[i] = W2_4[i];
    }
    __syncthreads();

    bias = ((const float4*)b2)[tid & 15];
    acc00 = bias.x; acc01 = bias.y; acc02 = bias.z; acc03 = bias.w;
    acc10 = bias.x; acc11 = bias.y; acc12 = bias.z; acc13 = bias.w;
    acc20 = bias.x; acc21 = bias.y; acc22 = bias.z; acc23 = bias.w;
    acc30 = bias.x; acc31 = bias.y; acc32 = bias.z; acc33 = bias.w;

    GEMM_LOOP(sH1)

    float sj0 = 0.f, sj1 = 0.f, sj2 = 0.f, sj3 = 0.f;
    float qj0 = 0.f, qj1 = 0.f, qj2 = 0.f, qj3 = 0.f;
    {
        int node = n0 + nr;
        float4 r;
        if (node + 0 < nNodes) {
            r.x = fmaxf(acc00, 0.f); r.y = fmaxf(acc01, 0.f); r.z = fmaxf(acc02, 0.f); r.w = fmaxf(acc03, 0.f);
            h_out4[(size_t)(node + 0) * 16 + (fc >> 2)] = r;
            sj0 += r.x; qj0 += r.x * r.x; sj1 += r.y; qj1 += r.y * r.y;
            sj2 += r.z; qj2 += r.z * r.z; sj3 += r.w; qj3 += r.w * r.w;
        }
        if (node + 1 < nNodes) {
            r.x = fmaxf(acc10, 0.f); r.y = fmaxf(acc11, 0.f); r.z = fmaxf(acc12, 0.f); r.w = fmaxf(acc13, 0.f);
            h_out4[(size_t)(node + 1) * 16 + (fc >> 2)] = r;
            sj0 += r.x; qj0 += r.x * r.x; sj1 += r.y; qj1 += r.y * r.y;
            sj2 += r.z; qj2 += r.z * r.z; sj3 += r.w; qj3 += r.w * r.w;
        }
        if (node + 2 < nNodes) {
            r.x = fmaxf(acc20, 0.f); r.y = fmaxf(acc21, 0.f); r.z = fmaxf(acc22, 0.f); r.w = fmaxf(acc23, 0.f);
            h_out4[(size_t)(node + 2) * 16 + (fc >> 2)] = r;
            sj0 += r.x; qj0 += r.x * r.x; sj1 += r.y; qj1 += r.y * r.y;
            sj2 += r.z; qj2 += r.z * r.z; sj3 += r.w; qj3 += r.w * r.w;
        }
        if (node + 3 < nNodes) {
            r.x = fmaxf(acc30, 0.f); r.y = fmaxf(acc31, 0.f); r.z = fmaxf(acc32, 0.f); r.w = fmaxf(acc33, 0.f);
            h_out4[(size_t)(node + 3) * 16 + (fc >> 2)] = r;
            sj0 += r.x; qj0 += r.x * r.x; sj1 += r.y; qj1 += r.y * r.y;
            sj2 += r.z; qj2 += r.z * r.z; sj3 += r.w; qj3 += r.w * r.w;
        }
    }

    float* sS = sA;
    float* sQ = sA + 1024;
    int rrow = tid >> 4;
    sS[rrow * 64 + fc + 0] = sj0; sS[rrow * 64 + fc + 1] = sj1;
    sS[rrow * 64 + fc + 2] = sj2; sS[rrow * 64 + fc + 3] = sj3;
    sQ[rrow * 64 + fc + 0] = qj0; sQ[rrow * 64 + fc + 1] = qj1;
    sQ[rrow * 64 + fc + 2] = qj2; sQ[rrow * 64 + fc + 3] = qj3;
    __syncthreads();
    if (tid < 64) {
        float S = 0.f;
#pragma unroll
        for (int r = 0; r < 16; ++r) S += sS[r * 64 + tid];
        atomicAdd(&stats[tid], S);
    } else if (tid < 128) {
        int f = tid - 64;
        float Q = 0.f;
#pragma unroll
        for (int r = 0; r < 16; ++r) Q += sQ[r * 64 + f];
        atomicAdd(&stats[64 + f], Q);
    }
}

// ---------------- pooling (BN3 fused) + final GEMV ----------------
__device__ __forceinline__ int lower_bound_dev(const int* a, int n, int key) {
    int lo = 0, hi = n;
    while (lo < hi) {
        int mid = (lo + hi) >> 1;
        if (a[mid] < key) lo = mid + 1; else hi = mid;
    }
    return lo;
}

__global__ __launch_bounds__(256) void k_pool(const float4* __restrict__ x4,
                                              const int* __restrict__ batch,
                                              const float* __restrict__ stats,
                                              const float* __restrict__ gamma,
                                              const float* __restrict__ beta,
                                              const float* __restrict__ Wf,
                                              const float* __restrict__ bf,
                                              float* __restrict__ out,
                                              int nNodes, float invN) {
    int wid = threadIdx.x >> 6;
    int lane = threadIdx.x & 63;
    int grp = lane >> 4;
    int l16 = lane & 15;
    int g = blockIdx.x * 4 + wid;

    float4 sc, sh;
    {
        float4 s  = ((const float4*)stats)[l16];
        float4 q  = ((const float4*)stats)[16 + l16];
        float4 ga = ((const float4*)gamma)[l16];
        float4 be = ((const float4*)beta)[l16];
        float m;
        m = s.x * invN; sc.x = ga.x * rsqrtf(q.x * invN - m * m + 1e-5f); sh.x = be.x - m * sc.x;
        m = s.y * invN; sc.y = ga.y * rsqrtf(q.y * invN - m * m + 1e-5f); sh.y = be.y - m * sc.y;
        m = s.z * invN; sc.z = ga.z * rsqrtf(q.z * invN - m * m + 1e-5f); sh.z = be.z - m * sc.z;
        m = s.w * invN; sc.w = ga.w * rsqrtf(q.w * invN - m * m + 1e-5f); sh.w = be.w - m * sc.w;
    }

    int lo = lower_bound_dev(batch, nNodes, g);
    int hi = lower_bound_dev(batch, nNodes, g + 1);

    float4 acc = f4zero();
    for (int r = lo + grp; r < hi; r += 4) {
        float4 v = x4[(size_t)r * 16 + l16];
        acc.x += fmaxf(fmaf(v.x, sc.x, sh.x), 0.f);
        acc.y += fmaxf(fmaf(v.y, sc.y, sh.y), 0.f);
        acc.z += fmaxf(fmaf(v.z, sc.z, sh.z), 0.f);
        acc.w += fmaxf(fmaf(v.w, sc.w, sh.w), 0.f);
    }
    acc.x += __shfl_xor(acc.x, 16, 64); acc.y += __shfl_xor(acc.y, 16, 64);
    acc.z += __shfl_xor(acc.z, 16, 64); acc.w += __shfl_xor(acc.w, 16, 64);
    acc.x += __shfl_xor(acc.x, 32, 64); acc.y += __shfl_xor(acc.y, 32, 64);
    acc.z += __shfl_xor(acc.z, 32, 64); acc.w += __shfl_xor(acc.w, 32, 64);

    float4 wf = ((const float4*)Wf)[l16];
    float p = acc.x * wf.x + acc.y * wf.y + acc.z * wf.z + acc.w * wf.w;
    p += __shfl_xor(p, 1, 64);
    p += __shfl_xor(p, 2, 64);
    p += __shfl_xor(p, 4, 64);
    p += __shfl_xor(p, 8, 64);
    if (lane == 0) out[g] = p + bf[0];
}

extern "C" void kernel_launch(void* const* d_in, const int* in_sizes, int n_in,
                              void* d_out, int out_size, void* d_ws, size_t ws_size,
                              hipStream_t stream) {
    const float* x_in  = (const float*)d_in[0];
    const int*   ei    = (const int*)d_in[1];
    const int*   batch = (const int*)d_in[2];
    const float* W1    = (const float*)d_in[3];
    const float* b1    = (const float*)d_in[4];
    const float* W2    = (const float*)d_in[5];
    const float* b2    = (const float*)d_in[6];
    const float* gamma = (const float*)d_in[7];
    const float* beta  = (const float*)d_in[8];
    const float* Wf    = (const float*)d_in[9];
    const float* bf    = (const float*)d_in[10];

    const int nNodes = in_sizes[0] / HIDDEN_C;   // 50000 (pack assumes <= 65536)
    const int nE = in_sizes[1] / 2;              // 800000
    const int* src = ei;
    const int* dst = ei + nE;

    const int nBuckets = (nNodes + 63) / 64;     // 782
    const int nTot = nBuckets * NCHUNK;          // 200192
    const int chunkSz = (nE + NCHUNK - 1) / NCHUNK;  // 3125
    const int scanBlocks = (nTot + 1023) / 1024;     // 196 (<=256)
    const float invN = 1.f / (float)nNodes;

    const size_t NB = (size_t)nNodes * HIDDEN_C * sizeof(float);  // 12.8 MB
    char* ws = (char*)d_ws;
    float*    bufA    = (float*)ws;
    float*    bufB    = (float*)(ws + NB);
    float*    stats   = (float*)(ws + 2 * NB);            // 3 x 128 floats
    int*      rowptr  = (int*)(ws + 2 * NB + 4096);       // nNodes+1
    int*      partial = rowptr + nNodes + 64;             // 256
    int*      col     = partial + 256;                    // nE
    // transient CSR-build scratch aliased into bufB (bufB first written at layer 1)
    unsigned* ebuf    = (unsigned*)bufB;                  // nE (3.2MB)
    int*      cnt     = (int*)(bufB + nE);                // nTot (0.8MB)
    int*      eoff    = cnt + nTot + 64;                  // nTot (0.8MB)

    const int mlpGrid = (nNodes + 63) / 64;
    const int aggGrid = (nNodes + 3) / 4;

    // ---- CSR build via 64-node buckets (line-friendly writes) ----
    k_bcount<<<NCHUNK, 256, 0, stream>>>(dst, cnt, stats, nE, chunkSz, nBuckets);
    k_blocksum<<<scanBlocks, 256, 0, stream>>>(cnt, partial, nTot);
    k_scanpartial<<<1, 256, 0, stream>>>(partial, rowptr + nNodes, scanBlocks, nE);
    k_writeptr<<<scanBlocks, 256, 0, stream>>>(cnt, partial, eoff, nTot);
    k_bscatter<<<NCHUNK, 256, 0, stream>>>(src, dst, eoff, ebuf, nE, chunkSz, nBuckets);
    k_bfill<<<nBuckets, 256, 0, stream>>>(ebuf, eoff, rowptr, col, nNodes, nE, nBuckets);

    // ---- 3 layers: split agg (gather) + MLP ----
    const float* prev_h = x_in;
    float* cur = bufA;
    for (int i = 0; i < 3; ++i) {
        if (i == 0) {
            k_aggbn<false><<<aggGrid, 256, 0, stream>>>((const float4*)prev_h, rowptr, col,
                                                        nullptr, nullptr, nullptr,
                                                        (float4*)cur, nNodes, invN);
        } else {
            k_aggbn<true><<<aggGrid, 256, 0, stream>>>((const float4*)prev_h, rowptr, col,
                                                       stats + (size_t)(i - 1) * 128,
                                                       gamma + (size_t)(i - 1) * 64,
                                                       beta + (size_t)(i - 1) * 64,
                                                       (float4*)cur, nNodes, invN);
        }
        k_mlp<<<mlpGrid, 256, 0, stream>>>((const float4*)cur, (float4*)cur,
                                           (const float4*)(W1 + (size_t)i * 4096), b1 + (size_t)i * 64,
                                           (const float4*)(W2 + (size_t)i * 4096), b2 + (size_t)i * 64,
                                           stats + (size_t)i * 128, nNodes);
        prev_h = cur;
        cur = (cur == bufA) ? bufB : bufA;
    }

    k_pool<<<64, 256, 0, stream>>>((const float4*)prev_h, batch,
                                   stats + 256, gamma + 128, beta + 128,
                                   Wf, bf, (float*)d_out, nNodes, invN);
}

// Round 10
// 250.988 us; speedup vs baseline: 1.6462x; 1.0002x over previous
//
#include <hip/hip_runtime.h>

#define HIDDEN_C 64
#define NCHUNK 256

typedef __attribute__((ext_vector_type(8))) short bf16x8;
typedef __attribute__((ext_vector_type(8))) unsigned short u16x8;
typedef __attribute__((ext_vector_type(4))) float f32x4;

__device__ __forceinline__ float4 f4zero() { return make_float4(0.f, 0.f, 0.f, 0.f); }

__device__ __forceinline__ unsigned short f2bf(float f) {
    unsigned u = __float_as_uint(f);
    u += 0x7FFF + ((u >> 16) & 1);          // round-to-nearest-even
    return (unsigned short)(u >> 16);
}
__device__ __forceinline__ float bf2f(unsigned short h) {
    return __uint_as_float(((unsigned)h) << 16);
}

// ---------------- generic exclusive scan ----------------
__global__ __launch_bounds__(256) void k_blocksum(const int* __restrict__ deg,
                                                  int* __restrict__ partial, int n) {
    int base = blockIdx.x * 1024 + threadIdx.x * 4;
    int s = 0;
#pragma unroll
    for (int k = 0; k < 4; ++k) {
        int i = base + k;
        if (i < n) s += deg[i];
    }
    __shared__ int red[256];
    red[threadIdx.x] = s;
    __syncthreads();
    for (int d = 128; d > 0; d >>= 1) {
        if (threadIdx.x < d) red[threadIdx.x] += red[threadIdx.x + d];
        __syncthreads();
    }
    if (threadIdx.x == 0) partial[blockIdx.x] = red[0];
}

__global__ __launch_bounds__(256) void k_scanpartial(int* __restrict__ partial,
                                                     int* __restrict__ last_slot,
                                                     int nBlocks, int nE) {
    __shared__ int buf[256];
    int tid = threadIdx.x;
    int v = (tid < nBlocks) ? partial[tid] : 0;
    buf[tid] = v;
    __syncthreads();
    for (int d = 1; d < 256; d <<= 1) {
        int t = (tid >= d) ? buf[tid - d] : 0;
        __syncthreads();
        buf[tid] += t;
        __syncthreads();
    }
    if (tid < nBlocks) partial[tid] = buf[tid] - v;
    if (tid == 0) last_slot[0] = nE;
}

__global__ __launch_bounds__(256) void k_writeptr(const int* __restrict__ deg,
                                                  const int* __restrict__ partial,
                                                  int* __restrict__ outp, int n) {
    int tid = threadIdx.x;
    int base = blockIdx.x * 1024 + tid * 4;
    int d[4];
    int s = 0;
#pragma unroll
    for (int k = 0; k < 4; ++k) {
        int i = base + k;
        d[k] = (i < n) ? deg[i] : 0;
        s += d[k];
    }
    __shared__ int buf[256];
    buf[tid] = s;
    __syncthreads();
    for (int dd = 1; dd < 256; dd <<= 1) {
        int t = (tid >= dd) ? buf[tid - dd] : 0;
        __syncthreads();
        buf[tid] += t;
        __syncthreads();
    }
    int off = partial[blockIdx.x] + buf[tid] - s;
#pragma unroll
    for (int k = 0; k < 4; ++k) {
        int i = base + k;
        if (i < n) {
            outp[i] = off;
            off += d[k];
        }
    }
}

// ---------------- bucket partition (bucket = dst>>6) ----------------
__global__ __launch_bounds__(256) void k_bcount(const int* __restrict__ dst,
                                                int* __restrict__ cnt,
                                                float* __restrict__ statsZ,
                                                int nE, int chunkSz, int nBuckets) {
    __shared__ int h[1024];
    int c = blockIdx.x, tid = threadIdx.x;
    if (c == 0) {
        for (int i = tid; i < 384; i += 256) statsZ[i] = 0.f;
    }
    for (int i = tid; i < nBuckets; i += 256) h[i] = 0;
    __syncthreads();
    int beg = c * chunkSz;
    int end = beg + chunkSz; if (end > nE) end = nE;
    int e = beg + tid;
    for (; e + 256 < end; e += 512) {
        int d0 = dst[e];
        int d1 = dst[e + 256];
        atomicAdd(&h[d0 >> 6], 1);
        atomicAdd(&h[d1 >> 6], 1);
    }
    if (e < end) atomicAdd(&h[dst[e] >> 6], 1);
    __syncthreads();
    for (int i = tid; i < nBuckets; i += 256) cnt[i * NCHUNK + c] = h[i];
}

__global__ __launch_bounds__(256) void k_bscatter(const int* __restrict__ src,
                                                  const int* __restrict__ dst,
                                                  const int* __restrict__ eoff,
                                                  unsigned* __restrict__ ebuf,
                                                  int nE, int chunkSz, int nBuckets) {
    __shared__ int cur[1024];
    int c = blockIdx.x, tid = threadIdx.x;
    for (int i = tid; i < nBuckets; i += 256) cur[i] = eoff[i * NCHUNK + c];
    __syncthreads();
    int beg = c * chunkSz;
    int end = beg + chunkSz; if (end > nE) end = nE;
    int e = beg + tid;
    for (; e + 256 < end; e += 512) {
        int d0 = dst[e];
        int d1 = dst[e + 256];
        int s0 = src[e];
        int s1 = src[e + 256];
        int p0 = atomicAdd(&cur[d0 >> 6], 1);
        int p1 = atomicAdd(&cur[d1 >> 6], 1);
        ebuf[p0] = ((unsigned)(d0 & 63) << 16) | (unsigned)s0;  // nNodes<=65536
        ebuf[p1] = ((unsigned)(d1 & 63) << 16) | (unsigned)s1;
    }
    if (e < end) {
        int d = dst[e];
        int pos = atomicAdd(&cur[d >> 6], 1);
        ebuf[pos] = ((unsigned)(d & 63) << 16) | (unsigned)src[e];
    }
}

__global__ __launch_bounds__(256) void k_bfill(const unsigned* __restrict__ ebuf,
                                               const int* __restrict__ eoff,
                                               int* __restrict__ rowptr,
                                               int* __restrict__ col,
                                               int nNodes, int nE, int nBuckets) {
    __shared__ int deg[64], cur[64];
    int b = blockIdx.x, tid = threadIdx.x;
    int lo = eoff[b * NCHUNK];
    int hi = (b + 1 < nBuckets) ? eoff[(b + 1) * NCHUNK] : nE;
    if (tid < 64) deg[tid] = 0;
    __syncthreads();
    for (int e = lo + tid; e < hi; e += 256) atomicAdd(&deg[ebuf[e] >> 16], 1);
    __syncthreads();
    if (tid < 64) {
        int d = deg[tid];
        int s = d;
        for (int o = 1; o < 64; o <<= 1) {
            int t = __shfl_up(s, o, 64);
            if (tid >= o) s += t;
        }
        int st = s - d;
        cur[tid] = lo + st;
        int node = b * 64 + tid;
        if (node < nNodes) rowptr[node] = lo + st;
    }
    __syncthreads();
    for (int e = lo + tid; e < hi; e += 256) {
        unsigned pk = ebuf[e];
        int pos = atomicAdd(&cur[pk >> 16], 1);
        col[pos] = (int)(pk & 0xFFFFu);
    }
}

// ---------------- fused BN(prev layer) + gather aggregation (fp32) ----------------
template <bool DOBN>
__global__ __launch_bounds__(256) void k_aggbn(const float4* __restrict__ x4,
                                               const int* __restrict__ rowptr,
                                               const int* __restrict__ col,
                                               const float* __restrict__ stats,
                                               const float* __restrict__ gamma,
                                               const float* __restrict__ beta,
                                               float4* __restrict__ h4,
                                               int nNodes, float invN) {
    int wid = threadIdx.x >> 6;
    int lane = threadIdx.x & 63;
    int grp = lane >> 4;
    int l16 = lane & 15;
    int n = blockIdx.x * 4 + wid;
    if (n >= nNodes) return;

    float4 sc = make_float4(1.f, 1.f, 1.f, 1.f);
    float4 sh = f4zero();
    if (DOBN) {
        float4 s  = ((const float4*)stats)[l16];
        float4 q  = ((const float4*)stats)[16 + l16];
        float4 ga = ((const float4*)gamma)[l16];
        float4 be = ((const float4*)beta)[l16];
        float m;
        m = s.x * invN; sc.x = ga.x * rsqrtf(q.x * invN - m * m + 1e-5f); sh.x = be.x - m * sc.x;
        m = s.y * invN; sc.y = ga.y * rsqrtf(q.y * invN - m * m + 1e-5f); sh.y = be.y - m * sc.y;
        m = s.z * invN; sc.z = ga.z * rsqrtf(q.z * invN - m * m + 1e-5f); sh.z = be.z - m * sc.z;
        m = s.w * invN; sc.w = ga.w * rsqrtf(q.w * invN - m * m + 1e-5f); sh.w = be.w - m * sc.w;
    }

    float4 acc = f4zero();
    {
        float4 v = x4[(size_t)n * 16 + l16];
        if (DOBN) {
            v.x = fmaxf(fmaf(v.x, sc.x, sh.x), 0.f);
            v.y = fmaxf(fmaf(v.y, sc.y, sh.y), 0.f);
            v.z = fmaxf(fmaf(v.z, sc.z, sh.z), 0.f);
            v.w = fmaxf(fmaf(v.w, sc.w, sh.w), 0.f);
        }
        if (grp == 0) acc = v;
    }

    int lo = rowptr[n], hi = rowptr[n + 1];
    int e = lo;
    for (; e + 8 <= hi; e += 8) {
        int i0 = col[e + grp];
        int i1 = col[e + 4 + grp];
        float4 v0 = x4[(size_t)i0 * 16 + l16];
        float4 v1 = x4[(size_t)i1 * 16 + l16];
        if (DOBN) {
            v0.x = fmaxf(fmaf(v0.x, sc.x, sh.x), 0.f);
            v0.y = fmaxf(fmaf(v0.y, sc.y, sh.y), 0.f);
            v0.z = fmaxf(fmaf(v0.z, sc.z, sh.z), 0.f);
            v0.w = fmaxf(fmaf(v0.w, sc.w, sh.w), 0.f);
            v1.x = fmaxf(fmaf(v1.x, sc.x, sh.x), 0.f);
            v1.y = fmaxf(fmaf(v1.y, sc.y, sh.y), 0.f);
            v1.z = fmaxf(fmaf(v1.z, sc.z, sh.z), 0.f);
            v1.w = fmaxf(fmaf(v1.w, sc.w, sh.w), 0.f);
        }
        acc.x += v0.x + v1.x; acc.y += v0.y + v1.y;
        acc.z += v0.z + v1.z; acc.w += v0.w + v1.w;
    }
    for (; e < hi; e += 4) {
        int ee = e + grp;
        bool ok = ee < hi;
        int idx = col[ok ? ee : (hi - 1)];
        float4 v = x4[(size_t)idx * 16 + l16];
        if (DOBN) {
            v.x = fmaxf(fmaf(v.x, sc.x, sh.x), 0.f);
            v.y = fmaxf(fmaf(v.y, sc.y, sh.y), 0.f);
            v.z = fmaxf(fmaf(v.z, sc.z, sh.z), 0.f);
            v.w = fmaxf(fmaf(v.w, sc.w, sh.w), 0.f);
        }
        if (ok) {
            acc.x += v.x; acc.y += v.y; acc.z += v.z; acc.w += v.w;
        }
    }

    acc.x += __shfl_xor(acc.x, 16, 64); acc.y += __shfl_xor(acc.y, 16, 64);
    acc.z += __shfl_xor(acc.z, 16, 64); acc.w += __shfl_xor(acc.w, 16, 64);
    acc.x += __shfl_xor(acc.x, 32, 64); acc.y += __shfl_xor(acc.y, 32, 64);
    acc.z += __shfl_xor(acc.z, 32, 64); acc.w += __shfl_xor(acc.w, 32, 64);

    if (lane < 16) h4[(size_t)n * 16 + l16] = acc;
}

// ---------------- MFMA 2-layer MLP (split bf16 hi/lo, fp32 I/O) + BN-stats ----------------
// 16x16x32 bf16 MFMA. A: row=l&15, k=(l>>4)*8+j ; B: col=l&15, same k ;
// D: col=l&15, row=(l>>4)*4+reg.  LDS tiles [row][k] bf16, 128B rows, 16B-chunk XOR swizzle.
__device__ __forceinline__ void stW_swz(unsigned short* base, int f, int k, unsigned short v) {
    *(unsigned short*)((char*)base + f * 128 + ((((k >> 3) << 4)) ^ ((f & 7) << 4)) + ((k & 7) << 1)) = v;
}

__global__ __launch_bounds__(256, 3) void k_mlp(const float* __restrict__ h_in,
                                                float* __restrict__ h_out,
                                                const float* __restrict__ W1,
                                                const float* __restrict__ b1,
                                                const float* __restrict__ W2,
                                                const float* __restrict__ b2,
                                                float* __restrict__ stats,
                                                int nNodes) {
    __shared__ __align__(16) char smem[49152];
    unsigned short* sA_hi = (unsigned short*)smem;            // 8KB [64][64] bf16 swz
    unsigned short* sA_lo = (unsigned short*)(smem + 8192);
    unsigned short* sW_hi = (unsigned short*)(smem + 16384);  // W^T [f][k]
    unsigned short* sW_lo = (unsigned short*)(smem + 24576);
    unsigned short* sH_hi = (unsigned short*)(smem + 32768);  // h1 [row][k]
    unsigned short* sH_lo = (unsigned short*)(smem + 40960);
    float* sOut = (float*)(smem + 16384);                     // 16KB fp32 out tile (over sW)
    float* sS   = (float*)(smem + 32768);                     // 2KB stats scratch (over sH)

    int tid = threadIdx.x;
    int n0 = blockIdx.x * 64;
    int lane = tid & 63;
    int w = tid >> 6;
    int lr = lane & 15;
    int q = lane >> 4;
    int r0 = w * 16;

    // --- stage A: fp32 h rows -> hi/lo bf16, swizzled 16B chunks ---
#pragma unroll
    for (int it = 0; it < 2; ++it) {
        int idx = it * 256 + tid;           // 512 groups of 8 floats
        int row = idx >> 3, ch = idx & 7;
        float4 v0 = f4zero(), v1 = f4zero();
        if (n0 + row < nNodes) {
            const float4* p = (const float4*)(h_in + (size_t)(n0 + row) * 64 + ch * 8);
            v0 = p[0]; v1 = p[1];
        }
        float f[8] = {v0.x, v0.y, v0.z, v0.w, v1.x, v1.y, v1.z, v1.w};
        u16x8 hv, lv;
#pragma unroll
        for (int j = 0; j < 8; ++j) {
            unsigned short h = f2bf(f[j]);
            hv[j] = h;
            lv[j] = f2bf(f[j] - bf2f(h));
        }
        int off = row * 128 + ((ch ^ (row & 7)) << 4);
        *(u16x8*)((char*)sA_hi + off) = hv;
        *(u16x8*)((char*)sA_lo + off) = lv;
    }
    // --- stage W1: fp32 [k][f] -> W^T hi/lo ---
    {
        int k = tid >> 2;
        int f0 = (tid & 3) * 16;
        const float4* wr = (const float4*)(W1 + k * 64 + f0);
#pragma unroll
        for (int j4 = 0; j4 < 4; ++j4) {
            float4 wv = wr[j4];
            int f = f0 + j4 * 4;
            float c[4] = {wv.x, wv.y, wv.z, wv.w};
#pragma unroll
            for (int j = 0; j < 4; ++j) {
                unsigned short h = f2bf(c[j]);
                stW_swz(sW_hi, f + j, k, h);
                stW_swz(sW_lo, f + j, k, f2bf(c[j] - bf2f(h)));
            }
        }
    }
    __syncthreads();

    f32x4 acc[4];

#define GEMM_SPLIT(AH, AL, BIAS)                                                  \
    {                                                                             \
        int rowA = r0 + lr;                                                       \
        const char* pah = (const char*)AH + rowA * 128;                           \
        const char* pal = (const char*)AL + rowA * 128;                           \
        int swzr = (rowA & 7) << 4;                                               \
        bf16x8 ah0 = *(const bf16x8*)(pah + ((q << 4) ^ swzr));                   \
        bf16x8 ah1 = *(const bf16x8*)(pah + (((4 + q) << 4) ^ swzr));             \
        bf16x8 al0 = *(const bf16x8*)(pal + ((q << 4) ^ swzr));                   \
        bf16x8 al1 = *(const bf16x8*)(pal + (((4 + q) << 4) ^ swzr));             \
        _Pragma("unroll")                                                         \
        for (int ct = 0; ct < 4; ++ct) {                                          \
            int f = ct * 16 + lr;                                                 \
            const char* pbh = (const char*)sW_hi + f * 128;                       \
            const char* pbl = (const char*)sW_lo + f * 128;                       \
            int swzf = (f & 7) << 4;                                              \
            bf16x8 bh0 = *(const bf16x8*)(pbh + ((q << 4) ^ swzf));               \
            bf16x8 bh1 = *(const bf16x8*)(pbh + (((4 + q) << 4) ^ swzf));         \
            bf16x8 bl0 = *(const bf16x8*)(pbl + ((q << 4) ^ swzf));               \
            bf16x8 bl1 = *(const bf16x8*)(pbl + (((4 + q) << 4) ^ swzf));         \
            float bias = BIAS[f];                                                 \
            f32x4 c = {bias, bias, bias, bias};                                   \
            c = __builtin_amdgcn_mfma_f32_16x16x32_bf16(al0, bh0, c, 0, 0, 0);    \
            c = __builtin_amdgcn_mfma_f32_16x16x32_bf16(al1, bh1, c, 0, 0, 0);    \
            c = __builtin_amdgcn_mfma_f32_16x16x32_bf16(ah0, bl0, c, 0, 0, 0);    \
            c = __builtin_amdgcn_mfma_f32_16x16x32_bf16(ah1, bl1, c, 0, 0, 0);    \
            c = __builtin_amdgcn_mfma_f32_16x16x32_bf16(ah0, bh0, c, 0, 0, 0);    \
            c = __builtin_amdgcn_mfma_f32_16x16x32_bf16(ah1, bh1, c, 0, 0, 0);    \
            acc[ct] = c;                                                          \
        }                                                                         \
    }

    // ---- GEMM1: h1 = relu(h @ W1 + b1) ----
    GEMM_SPLIT(sA_hi, sA_lo, b1)

    // h1 -> sH hi/lo (swizzled [row][k])
#pragma unroll
    for (int ct = 0; ct < 4; ++ct) {
        int f = ct * 16 + lr;
#pragma unroll
        for (int rg = 0; rg < 4; ++rg) {
            int row = r0 + q * 4 + rg;
            float v = fmaxf(acc[ct][rg], 0.f);
            unsigned short h = f2bf(v);
            stW_swz(sH_hi, row, f, h);
            stW_swz(sH_lo, row, f, f2bf(v - bf2f(h)));
        }
    }
    __syncthreads();   // W1 reads done, sH complete

    // --- stage W2 ---
    {
        int k = tid >> 2;
        int f0 = (tid & 3) * 16;
        const float4* wr = (const float4*)(W2 + k * 64 + f0);
#pragma unroll
        for (int j4 = 0; j4 < 4; ++j4) {
            float4 wv = wr[j4];
            int f = f0 + j4 * 4;
            float c[4] = {wv.x, wv.y, wv.z, wv.w};
#pragma unroll
            for (int j = 0; j < 4; ++j) {
                unsigned short h = f2bf(c[j]);
                stW_swz(sW_hi, f + j, k, h);
                stW_swz(sW_lo, f + j, k, f2bf(c[j] - bf2f(h)));
            }
        }
    }
    __syncthreads();

    // ---- GEMM2: out = relu(h1 @ W2 + b2) ----
    GEMM_SPLIT(sH_hi, sH_lo, b2)

    __syncthreads();   // all GEMM2 LDS reads done; sW region reusable as sOut

    // out tile -> sOut (fp32, unswizzled [row][f])
#pragma unroll
    for (int ct = 0; ct < 4; ++ct) {
        int f = ct * 16 + lr;
#pragma unroll
        for (int rg = 0; rg < 4; ++rg) {
            int row = r0 + q * 4 + rg;
            sOut[row * 64 + f] = fmaxf(acc[ct][rg], 0.f);
        }
    }
    __syncthreads();

    // stats partials from sOut (exact values next layer reads)
    {
        int f = tid & 63;
        int rg4 = tid >> 6;
        float s = 0.f, qq = 0.f;
#pragma unroll
        for (int i = 0; i < 16; ++i) {
            int row = rg4 * 16 + i;
            if (n0 + row < nNodes) {
                float v = sOut[row * 64 + f];
                s += v; qq += v * v;
            }
        }
        sS[rg4 * 64 + f] = s;
        sS[256 + rg4 * 64 + f] = qq;
    }
    // coalesced global writes
#pragma unroll
    for (int it = 0; it < 4; ++it) {
        int idx = it * 256 + tid;        // 1024 float4 groups
        int row = idx >> 4, c4 = idx & 15;
        if (n0 + row < nNodes)
            *(float4*)(h_out + (size_t)(n0 + row) * 64 + c4 * 4) = ((const float4*)sOut)[idx];
    }
    __syncthreads();
    if (tid < 64) {
        float S = sS[tid] + sS[64 + tid] + sS[128 + tid] + sS[192 + tid];
        atomicAdd(&stats[tid], S);
    } else if (tid < 128) {
        int f = tid - 64;
        float Q = sS[256 + f] + sS[320 + f] + sS[384 + f] + sS[448 + f];
        atomicAdd(&stats[64 + f], Q);
    }
#undef GEMM_SPLIT
}

// ---------------- pooling (BN3 fused) + final GEMV ----------------
__device__ __forceinline__ int lower_bound_dev(const int* a, int n, int key) {
    int lo = 0, hi = n;
    while (lo < hi) {
        int mid = (lo + hi) >> 1;
        if (a[mid] < key) lo = mid + 1; else hi = mid;
    }
    return lo;
}

__global__ __launch_bounds__(256) void k_pool(const float4* __restrict__ x4,
                                              const int* __restrict__ batch,
                                              const float* __restrict__ stats,
                                              const float* __restrict__ gamma,
                                              const float* __restrict__ beta,
                                              const float* __restrict__ Wf,
                                              const float* __restrict__ bf,
                                              float* __restrict__ out,
                                              int nNodes, float invN) {
    int wid = threadIdx.x >> 6;
    int lane = threadIdx.x & 63;
    int grp = lane >> 4;
    int l16 = lane & 15;
    int g = blockIdx.x * 4 + wid;

    float4 sc, sh;
    {
        float4 s  = ((const float4*)stats)[l16];
        float4 q  = ((const float4*)stats)[16 + l16];
        float4 ga = ((const float4*)gamma)[l16];
        float4 be = ((const float4*)beta)[l16];
        float m;
        m = s.x * invN; sc.x = ga.x * rsqrtf(q.x * invN - m * m + 1e-5f); sh.x = be.x - m * sc.x;
        m = s.y * invN; sc.y = ga.y * rsqrtf(q.y * invN - m * m + 1e-5f); sh.y = be.y - m * sc.y;
        m = s.z * invN; sc.z = ga.z * rsqrtf(q.z * invN - m * m + 1e-5f); sh.z = be.z - m * sc.z;
        m = s.w * invN; sc.w = ga.w * rsqrtf(q.w * invN - m * m + 1e-5f); sh.w = be.w - m * sc.w;
    }

    int lo = lower_bound_dev(batch, nNodes, g);
    int hi = lower_bound_dev(batch, nNodes, g + 1);

    float4 acc = f4zero();
    for (int r = lo + grp; r < hi; r += 4) {
        float4 v = x4[(size_t)r * 16 + l16];
        acc.x += fmaxf(fmaf(v.x, sc.x, sh.x), 0.f);
        acc.y += fmaxf(fmaf(v.y, sc.y, sh.y), 0.f);
        acc.z += fmaxf(fmaf(v.z, sc.z, sh.z), 0.f);
        acc.w += fmaxf(fmaf(v.w, sc.w, sh.w), 0.f);
    }
    acc.x += __shfl_xor(acc.x, 16, 64); acc.y += __shfl_xor(acc.y, 16, 64);
    acc.z += __shfl_xor(acc.z, 16, 64); acc.w += __shfl_xor(acc.w, 16, 64);
    acc.x += __shfl_xor(acc.x, 32, 64); acc.y += __shfl_xor(acc.y, 32, 64);
    acc.z += __shfl_xor(acc.z, 32, 64); acc.w += __shfl_xor(acc.w, 32, 64);

    float4 wf = ((const float4*)Wf)[l16];
    float p = acc.x * wf.x + acc.y * wf.y + acc.z * wf.z + acc.w * wf.w;
    p += __shfl_xor(p, 1, 64);
    p += __shfl_xor(p, 2, 64);
    p += __shfl_xor(p, 4, 64);
    p += __shfl_xor(p, 8, 64);
    if (lane == 0) out[g] = p + bf[0];
}

extern "C" void kernel_launch(void* const* d_in, const int* in_sizes, int n_in,
                              void* d_out, int out_size, void* d_ws, size_t ws_size,
                              hipStream_t stream) {
    const float* x_in  = (const float*)d_in[0];
    const int*   ei    = (const int*)d_in[1];
    const int*   batch = (const int*)d_in[2];
    const float* W1    = (const float*)d_in[3];
    const float* b1    = (const float*)d_in[4];
    const float* W2    = (const float*)d_in[5];
    const float* b2    = (const float*)d_in[6];
    const float* gamma = (const float*)d_in[7];
    const float* beta  = (const float*)d_in[8];
    const float* Wf    = (const float*)d_in[9];
    const float* bf    = (const float*)d_in[10];

    const int nNodes = in_sizes[0] / HIDDEN_C;   // 50000 (pack assumes <= 65536)
    const int nE = in_sizes[1] / 2;              // 800000
    const int* src = ei;
    const int* dst = ei + nE;

    const int nBuckets = (nNodes + 63) / 64;         // 782
    const int nTot = nBuckets * NCHUNK;              // 200192
    const int chunkSz = (nE + NCHUNK - 1) / NCHUNK;  // 3125
    const int scanBlocks = (nTot + 1023) / 1024;     // 196 (<=256)
    const float invN = 1.f / (float)nNodes;

    const size_t NB = (size_t)nNodes * HIDDEN_C * sizeof(float);  // 12.8 MB
    char* ws = (char*)d_ws;
    float*    bufA    = (float*)ws;
    float*    bufB    = (float*)(ws + NB);
    float*    stats   = (float*)(ws + 2 * NB);            // 3 x 128 floats
    int*      rowptr  = (int*)(ws + 2 * NB + 4096);       // nNodes+1
    int*      partial = rowptr + nNodes + 64;             // 256
    int*      col     = partial + 256;                    // nE
    // transient CSR-build scratch aliased into bufB (bufB first written at layer-1 agg)
    unsigned* ebuf    = (unsigned*)bufB;                  // nE (3.2MB)
    int*      cnt     = (int*)((char*)bufB + (size_t)nE * 4);  // nTot (0.8MB)
    int*      eoff    = cnt + nTot + 64;                  // nTot (0.8MB)

    const int mlpGrid = nBuckets;
    const int aggGrid = (nNodes + 3) / 4;

    // ---- CSR build via 64-node buckets ----
    k_bcount<<<NCHUNK, 256, 0, stream>>>(dst, cnt, stats, nE, chunkSz, nBuckets);
    k_blocksum<<<scanBlocks, 256, 0, stream>>>(cnt, partial, nTot);
    k_scanpartial<<<1, 256, 0, stream>>>(partial, rowptr + nNodes, scanBlocks, nE);
    k_writeptr<<<scanBlocks, 256, 0, stream>>>(cnt, partial, eoff, nTot);
    k_bscatter<<<NCHUNK, 256, 0, stream>>>(src, dst, eoff, ebuf, nE, chunkSz, nBuckets);
    k_bfill<<<nBuckets, 256, 0, stream>>>(ebuf, eoff, rowptr, col, nNodes, nE, nBuckets);

    // ---- 3 layers: agg (fp32) + MFMA MLP (split bf16) ----
    const float* prev_h = x_in;
    float* cur = bufA;
    for (int i = 0; i < 3; ++i) {
        if (i == 0) {
            k_aggbn<false><<<aggGrid, 256, 0, stream>>>((const float4*)prev_h, rowptr, col,
                                                        nullptr, nullptr, nullptr,
                                                        (float4*)cur, nNodes, invN);
        } else {
            k_aggbn<true><<<aggGrid, 256, 0, stream>>>((const float4*)prev_h, rowptr, col,
                                                       stats + (size_t)(i - 1) * 128,
                                                       gamma + (size_t)(i - 1) * 64,
                                                       beta + (size_t)(i - 1) * 64,
                                                       (float4*)cur, nNodes, invN);
        }
        k_mlp<<<mlpGrid, 256, 0, stream>>>(cur, cur,
                                           W1 + (size_t)i * 4096, b1 + (size_t)i * 64,
                                           W2 + (size_t)i * 4096, b2 + (size_t)i * 64,
                                           stats + (size_t)i * 128, nNodes);
        prev_h = cur;
        cur = (cur == bufA) ? bufB : bufA;
    }

    k_pool<<<64, 256, 0, stream>>>((const float4*)prev_h, batch,
                                   stats + 256, gamma + 128, beta + 128,
                                   Wf, bf, (float*)d_out, nNodes, invN);
}

// Round 11
// 244.417 us; speedup vs baseline: 1.6904x; 1.0269x over previous
//
#include <hip/hip_runtime.h>

#define HIDDEN_C 64
#define NCHUNK 256

typedef __attribute__((ext_vector_type(8))) short bf16x8;
typedef __attribute__((ext_vector_type(8))) unsigned short u16x8;
typedef __attribute__((ext_vector_type(4))) float f32x4;

__device__ __forceinline__ float4 f4zero() { return make_float4(0.f, 0.f, 0.f, 0.f); }

__device__ __forceinline__ unsigned short f2bf(float f) {
    unsigned u = __float_as_uint(f);
    u += 0x7FFF + ((u >> 16) & 1);          // round-to-nearest-even
    return (unsigned short)(u >> 16);
}
__device__ __forceinline__ float bf2f(unsigned short h) {
    return __uint_as_float(((unsigned)h) << 16);
}

// swizzled u16 index within a [64 rows][64 k] bf16 tile (128B rows, 16B-chunk XOR)
__device__ __forceinline__ int swz_idx(int row, int k) {
    return row * 64 + ((((k >> 3) ^ (row & 7)) << 3) | (k & 7));
}

// ---------------- generic exclusive scan ----------------
__global__ __launch_bounds__(256) void k_blocksum(const int* __restrict__ deg,
                                                  int* __restrict__ partial, int n) {
    int base = blockIdx.x * 1024 + threadIdx.x * 4;
    int s = 0;
#pragma unroll
    for (int k = 0; k < 4; ++k) {
        int i = base + k;
        if (i < n) s += deg[i];
    }
    __shared__ int red[256];
    red[threadIdx.x] = s;
    __syncthreads();
    for (int d = 128; d > 0; d >>= 1) {
        if (threadIdx.x < d) red[threadIdx.x] += red[threadIdx.x + d];
        __syncthreads();
    }
    if (threadIdx.x == 0) partial[blockIdx.x] = red[0];
}

__global__ __launch_bounds__(256) void k_scanpartial(int* __restrict__ partial,
                                                     int* __restrict__ last_slot,
                                                     int nBlocks, int nE) {
    __shared__ int buf[256];
    int tid = threadIdx.x;
    int v = (tid < nBlocks) ? partial[tid] : 0;
    buf[tid] = v;
    __syncthreads();
    for (int d = 1; d < 256; d <<= 1) {
        int t = (tid >= d) ? buf[tid - d] : 0;
        __syncthreads();
        buf[tid] += t;
        __syncthreads();
    }
    if (tid < nBlocks) partial[tid] = buf[tid] - v;
    if (tid == 0) last_slot[0] = nE;
}

__global__ __launch_bounds__(256) void k_writeptr(const int* __restrict__ deg,
                                                  const int* __restrict__ partial,
                                                  int* __restrict__ outp, int n) {
    int tid = threadIdx.x;
    int base = blockIdx.x * 1024 + tid * 4;
    int d[4];
    int s = 0;
#pragma unroll
    for (int k = 0; k < 4; ++k) {
        int i = base + k;
        d[k] = (i < n) ? deg[i] : 0;
        s += d[k];
    }
    __shared__ int buf[256];
    buf[tid] = s;
    __syncthreads();
    for (int dd = 1; dd < 256; dd <<= 1) {
        int t = (tid >= dd) ? buf[tid - dd] : 0;
        __syncthreads();
        buf[tid] += t;
        __syncthreads();
    }
    int off = partial[blockIdx.x] + buf[tid] - s;
#pragma unroll
    for (int k = 0; k < 4; ++k) {
        int i = base + k;
        if (i < n) {
            outp[i] = off;
            off += d[k];
        }
    }
}

// ---------------- bucket partition (bucket = dst>>6) ----------------
__global__ __launch_bounds__(256) void k_bcount(const int* __restrict__ dst,
                                                int* __restrict__ cnt,
                                                float* __restrict__ statsZ,
                                                int nE, int chunkSz, int nBuckets) {
    __shared__ int h[1024];
    int c = blockIdx.x, tid = threadIdx.x;
    if (c == 0) {
        for (int i = tid; i < 384; i += 256) statsZ[i] = 0.f;
    }
    for (int i = tid; i < nBuckets; i += 256) h[i] = 0;
    __syncthreads();
    int beg = c * chunkSz;
    int end = beg + chunkSz; if (end > nE) end = nE;
    int e = beg + tid;
    for (; e + 256 < end; e += 512) {
        int d0 = dst[e];
        int d1 = dst[e + 256];
        atomicAdd(&h[d0 >> 6], 1);
        atomicAdd(&h[d1 >> 6], 1);
    }
    if (e < end) atomicAdd(&h[dst[e] >> 6], 1);
    __syncthreads();
    for (int i = tid; i < nBuckets; i += 256) cnt[i * NCHUNK + c] = h[i];
}

__global__ __launch_bounds__(256) void k_bscatter(const int* __restrict__ src,
                                                  const int* __restrict__ dst,
                                                  const int* __restrict__ eoff,
                                                  unsigned* __restrict__ ebuf,
                                                  int nE, int chunkSz, int nBuckets) {
    __shared__ int cur[1024];
    int c = blockIdx.x, tid = threadIdx.x;
    for (int i = tid; i < nBuckets; i += 256) cur[i] = eoff[i * NCHUNK + c];
    __syncthreads();
    int beg = c * chunkSz;
    int end = beg + chunkSz; if (end > nE) end = nE;
    int e = beg + tid;
    for (; e + 256 < end; e += 512) {
        int d0 = dst[e];
        int d1 = dst[e + 256];
        int s0 = src[e];
        int s1 = src[e + 256];
        int p0 = atomicAdd(&cur[d0 >> 6], 1);
        int p1 = atomicAdd(&cur[d1 >> 6], 1);
        ebuf[p0] = ((unsigned)(d0 & 63) << 16) | (unsigned)s0;  // nNodes<=65536
        ebuf[p1] = ((unsigned)(d1 & 63) << 16) | (unsigned)s1;
    }
    if (e < end) {
        int d = dst[e];
        int pos = atomicAdd(&cur[d >> 6], 1);
        ebuf[pos] = ((unsigned)(d & 63) << 16) | (unsigned)src[e];
    }
}

__global__ __launch_bounds__(256) void k_bfill(const unsigned* __restrict__ ebuf,
                                               const int* __restrict__ eoff,
                                               int* __restrict__ rowptr,
                                               int* __restrict__ col,
                                               int nNodes, int nE, int nBuckets) {
    __shared__ int deg[64], cur[64];
    int b = blockIdx.x, tid = threadIdx.x;
    int lo = eoff[b * NCHUNK];
    int hi = (b + 1 < nBuckets) ? eoff[(b + 1) * NCHUNK] : nE;
    if (tid < 64) deg[tid] = 0;
    __syncthreads();
    for (int e = lo + tid; e < hi; e += 256) atomicAdd(&deg[ebuf[e] >> 16], 1);
    __syncthreads();
    if (tid < 64) {
        int d = deg[tid];
        int s = d;
        for (int o = 1; o < 64; o <<= 1) {
            int t = __shfl_up(s, o, 64);
            if (tid >= o) s += t;
        }
        int st = s - d;
        cur[tid] = lo + st;
        int node = b * 64 + tid;
        if (node < nNodes) rowptr[node] = lo + st;
    }
    __syncthreads();
    for (int e = lo + tid; e < hi; e += 256) {
        unsigned pk = ebuf[e];
        int pos = atomicAdd(&cur[pk >> 16], 1);
        col[pos] = (int)(pk & 0xFFFFu);
    }
}

// ---------------- weight prep: W[k][f] fp32 -> W^T hi/lo bf16 swizzled tiles ----------------
// 6 blocks: b = layer*2 + (0:W1, 1:W2). Output: wt[b] = [hi 4096 u16][lo 4096 u16]
__global__ __launch_bounds__(256) void k_wprep(const float* __restrict__ W1,
                                               const float* __restrict__ W2,
                                               unsigned short* __restrict__ wt) {
    __shared__ unsigned short s[8192];
    int b = blockIdx.x;
    int layer = b >> 1;
    const float* src = ((b & 1) ? W2 : W1) + (size_t)layer * 4096;
    int tid = threadIdx.x;
    int k = tid >> 2;
    int f0 = (tid & 3) * 16;
    const float* srcp = src + k * 64 + f0;
#pragma unroll
    for (int j4 = 0; j4 < 4; ++j4) {
        float4 wv = *(const float4*)(srcp + j4 * 4);
        float c[4] = {wv.x, wv.y, wv.z, wv.w};
        int f = f0 + j4 * 4;
#pragma unroll
        for (int j = 0; j < 4; ++j) {
            unsigned short h = f2bf(c[j]);
            int ix = swz_idx(f + j, k);
            s[ix] = h;
            s[4096 + ix] = f2bf(c[j] - bf2f(h));
        }
    }
    __syncthreads();
    uint4* dst = (uint4*)(wt + (size_t)b * 8192);
    const uint4* sp = (const uint4*)s;
#pragma unroll
    for (int it = 0; it < 4; ++it) dst[it * 256 + tid] = sp[it * 256 + tid];
}

// ---------------- fused BN(prev layer) + gather aggregation (fp32) ----------------
template <bool DOBN>
__global__ __launch_bounds__(256) void k_aggbn(const float4* __restrict__ x4,
                                               const int* __restrict__ rowptr,
                                               const int* __restrict__ col,
                                               const float* __restrict__ stats,
                                               const float* __restrict__ gamma,
                                               const float* __restrict__ beta,
                                               float4* __restrict__ h4,
                                               int nNodes, float invN) {
    int wid = threadIdx.x >> 6;
    int lane = threadIdx.x & 63;
    int grp = lane >> 4;
    int l16 = lane & 15;
    int n = blockIdx.x * 4 + wid;
    if (n >= nNodes) return;

    float4 sc = make_float4(1.f, 1.f, 1.f, 1.f);
    float4 sh = f4zero();
    if (DOBN) {
        float4 s  = ((const float4*)stats)[l16];
        float4 q  = ((const float4*)stats)[16 + l16];
        float4 ga = ((const float4*)gamma)[l16];
        float4 be = ((const float4*)beta)[l16];
        float m;
        m = s.x * invN; sc.x = ga.x * rsqrtf(q.x * invN - m * m + 1e-5f); sh.x = be.x - m * sc.x;
        m = s.y * invN; sc.y = ga.y * rsqrtf(q.y * invN - m * m + 1e-5f); sh.y = be.y - m * sc.y;
        m = s.z * invN; sc.z = ga.z * rsqrtf(q.z * invN - m * m + 1e-5f); sh.z = be.z - m * sc.z;
        m = s.w * invN; sc.w = ga.w * rsqrtf(q.w * invN - m * m + 1e-5f); sh.w = be.w - m * sc.w;
    }

    float4 acc = f4zero();
    {
        float4 v = x4[(size_t)n * 16 + l16];
        if (DOBN) {
            v.x = fmaxf(fmaf(v.x, sc.x, sh.x), 0.f);
            v.y = fmaxf(fmaf(v.y, sc.y, sh.y), 0.f);
            v.z = fmaxf(fmaf(v.z, sc.z, sh.z), 0.f);
            v.w = fmaxf(fmaf(v.w, sc.w, sh.w), 0.f);
        }
        if (grp == 0) acc = v;
    }

    int lo = rowptr[n], hi = rowptr[n + 1];
    int e = lo;
    for (; e + 8 <= hi; e += 8) {
        int i0 = col[e + grp];
        int i1 = col[e + 4 + grp];
        float4 v0 = x4[(size_t)i0 * 16 + l16];
        float4 v1 = x4[(size_t)i1 * 16 + l16];
        if (DOBN) {
            v0.x = fmaxf(fmaf(v0.x, sc.x, sh.x), 0.f);
            v0.y = fmaxf(fmaf(v0.y, sc.y, sh.y), 0.f);
            v0.z = fmaxf(fmaf(v0.z, sc.z, sh.z), 0.f);
            v0.w = fmaxf(fmaf(v0.w, sc.w, sh.w), 0.f);
            v1.x = fmaxf(fmaf(v1.x, sc.x, sh.x), 0.f);
            v1.y = fmaxf(fmaf(v1.y, sc.y, sh.y), 0.f);
            v1.z = fmaxf(fmaf(v1.z, sc.z, sh.z), 0.f);
            v1.w = fmaxf(fmaf(v1.w, sc.w, sh.w), 0.f);
        }
        acc.x += v0.x + v1.x; acc.y += v0.y + v1.y;
        acc.z += v0.z + v1.z; acc.w += v0.w + v1.w;
    }
    for (; e < hi; e += 4) {
        int ee = e + grp;
        bool ok = ee < hi;
        int idx = col[ok ? ee : (hi - 1)];
        float4 v = x4[(size_t)idx * 16 + l16];
        if (DOBN) {
            v.x = fmaxf(fmaf(v.x, sc.x, sh.x), 0.f);
            v.y = fmaxf(fmaf(v.y, sc.y, sh.y), 0.f);
            v.z = fmaxf(fmaf(v.z, sc.z, sh.z), 0.f);
            v.w = fmaxf(fmaf(v.w, sc.w, sh.w), 0.f);
        }
        if (ok) {
            acc.x += v.x; acc.y += v.y; acc.z += v.z; acc.w += v.w;
        }
    }

    acc.x += __shfl_xor(acc.x, 16, 64); acc.y += __shfl_xor(acc.y, 16, 64);
    acc.z += __shfl_xor(acc.z, 16, 64); acc.w += __shfl_xor(acc.w, 16, 64);
    acc.x += __shfl_xor(acc.x, 32, 64); acc.y += __shfl_xor(acc.y, 32, 64);
    acc.z += __shfl_xor(acc.z, 32, 64); acc.w += __shfl_xor(acc.w, 32, 64);

    if (lane < 16) h4[(size_t)n * 16 + l16] = acc;
}

// ---------------- MFMA 2-layer MLP (split bf16 hi/lo, fp32 I/O, precomputed W^T) ----------------
// 16x16x32 bf16 MFMA. A: row=l&15, k=(l>>4)*8+j ; B: col=l&15, same k ;
// D: col=l&15, row=(l>>4)*4+reg.
__global__ __launch_bounds__(256, 5) void k_mlp(const float* __restrict__ h_in,
                                                float* __restrict__ h_out,
                                                const unsigned short* __restrict__ wt1,
                                                const float* __restrict__ b1,
                                                const unsigned short* __restrict__ wt2,
                                                const float* __restrict__ b2,
                                                float* __restrict__ stats,
                                                int nNodes) {
    __shared__ __align__(16) unsigned short smem16[16384];   // 32KB -> 5 blocks/CU
    unsigned short* sA_hi = smem16;            // [64][64] bf16 swz (A, then h1)
    unsigned short* sA_lo = smem16 + 4096;
    unsigned short* sW_hi = smem16 + 8192;     // W^T tiles (W1, then W2)
    unsigned short* sW_lo = smem16 + 12288;

    int tid = threadIdx.x;
    int n0 = blockIdx.x * 64;
    int lane = tid & 63;
    int w = tid >> 6;
    int lr = lane & 15;
    int q = lane >> 4;
    int r0 = w * 16;

    // --- stage A: fp32 h rows -> hi/lo bf16, vector swizzled 16B chunks ---
#pragma unroll
    for (int it = 0; it < 2; ++it) {
        int idx = it * 256 + tid;           // 512 groups of 8 floats
        int row = idx >> 3, ch = idx & 7;
        float4 v0 = f4zero(), v1 = f4zero();
        if (n0 + row < nNodes) {
            const float4* p = (const float4*)(h_in + (size_t)(n0 + row) * 64 + ch * 8);
            v0 = p[0]; v1 = p[1];
        }
        float f[8] = {v0.x, v0.y, v0.z, v0.w, v1.x, v1.y, v1.z, v1.w};
        u16x8 hv, lv;
#pragma unroll
        for (int j = 0; j < 8; ++j) {
            unsigned short h = f2bf(f[j]);
            hv[j] = h;
            lv[j] = f2bf(f[j] - bf2f(h));
        }
        int off = row * 64 + ((ch ^ (row & 7)) << 3);
        *(u16x8*)(sA_hi + off) = hv;
        *(u16x8*)(sA_lo + off) = lv;
    }
    // --- copy precomputed W1^T hi/lo (16KB) ---
    {
        uint4* d = (uint4*)sW_hi;
        const uint4* s = (const uint4*)wt1;
#pragma unroll
        for (int it = 0; it < 4; ++it) d[it * 256 + tid] = s[it * 256 + tid];
    }
    __syncthreads();

    f32x4 acc[4];

#define GEMM_SPLIT(AHI, ALO, BIAS)                                               \
    {                                                                            \
        int rowA = r0 + lr;                                                      \
        const unsigned short* pah = AHI + rowA * 64;                             \
        const unsigned short* pal = ALO + rowA * 64;                             \
        int sr = rowA & 7;                                                       \
        bf16x8 ah0 = *(const bf16x8*)(pah + ((q ^ sr) << 3));                    \
        bf16x8 ah1 = *(const bf16x8*)(pah + (((4 + q) ^ sr) << 3));              \
        bf16x8 al0 = *(const bf16x8*)(pal + ((q ^ sr) << 3));                    \
        bf16x8 al1 = *(const bf16x8*)(pal + (((4 + q) ^ sr) << 3));              \
        _Pragma("unroll")                                                        \
        for (int ct = 0; ct < 4; ++ct) {                                         \
            int f = ct * 16 + lr;                                                \
            const unsigned short* pbh = sW_hi + f * 64;                          \
            const unsigned short* pbl = sW_lo + f * 64;                          \
            int sf = f & 7;                                                      \
            bf16x8 bh0 = *(const bf16x8*)(pbh + ((q ^ sf) << 3));                \
            bf16x8 bh1 = *(const bf16x8*)(pbh + (((4 + q) ^ sf) << 3));          \
            bf16x8 bl0 = *(const bf16x8*)(pbl + ((q ^ sf) << 3));                \
            bf16x8 bl1 = *(const bf16x8*)(pbl + (((4 + q) ^ sf) << 3));          \
            float bias = BIAS[f];                                                \
            f32x4 c = {bias, bias, bias, bias};                                  \
            c = __builtin_amdgcn_mfma_f32_16x16x32_bf16(al0, bh0, c, 0, 0, 0);   \
            c = __builtin_amdgcn_mfma_f32_16x16x32_bf16(al1, bh1, c, 0, 0, 0);   \
            c = __builtin_amdgcn_mfma_f32_16x16x32_bf16(ah0, bl0, c, 0, 0, 0);   \
            c = __builtin_amdgcn_mfma_f32_16x16x32_bf16(ah1, bl1, c, 0, 0, 0);   \
            c = __builtin_amdgcn_mfma_f32_16x16x32_bf16(ah0, bh0, c, 0, 0, 0);   \
            c = __builtin_amdgcn_mfma_f32_16x16x32_bf16(ah1, bh1, c, 0, 0, 0);   \
            acc[ct] = c;                                                         \
        }                                                                        \
    }

    // ---- GEMM1: h1 = relu(h @ W1 + b1) ----
    GEMM_SPLIT(sA_hi, sA_lo, b1)

    __syncthreads();   // all GEMM1 LDS reads done; sA & sW reusable

    // h1 -> sA region hi/lo (scalar swz writes); copy W2^T -> sW
#pragma unroll
    for (int ct = 0; ct < 4; ++ct) {
        int f = ct * 16 + lr;
#pragma unroll
        for (int rg = 0; rg < 4; ++rg) {
            int row = r0 + q * 4 + rg;
            float v = fmaxf(acc[ct][rg], 0.f);
            unsigned short h = f2bf(v);
            int ix = swz_idx(row, f);
            sA_hi[ix] = h;
            sA_lo[ix] = f2bf(v - bf2f(h));
        }
    }
    {
        uint4* d = (uint4*)sW_hi;
        const uint4* s = (const uint4*)wt2;
#pragma unroll
        for (int it = 0; it < 4; ++it) d[it * 256 + tid] = s[it * 256 + tid];
    }
    __syncthreads();

    // ---- GEMM2: out = relu(h1 @ W2 + b2) ----
    GEMM_SPLIT(sA_hi, sA_lo, b2)

    __syncthreads();   // all GEMM2 LDS reads done; sW region reusable as stats scratch
#undef GEMM_SPLIT

    float* sS = (float*)sW_hi;     // 256 floats
    float* sQ = sS + 256;          // 256 floats

    // epilogue: relu -> global store (64B-coalesced per instruction) + register stats
#pragma unroll
    for (int ct = 0; ct < 4; ++ct) {
        int f = ct * 16 + lr;
        float sp = 0.f, qp = 0.f;
#pragma unroll
        for (int rg = 0; rg < 4; ++rg) {
            int row = r0 + q * 4 + rg;
            float v = fmaxf(acc[ct][rg], 0.f);
            if (n0 + row < nNodes) {
                h_out[(size_t)(n0 + row) * 64 + f] = v;
                sp += v;
                qp += v * v;
            }
        }
        sp += __shfl_xor(sp, 16, 64); qp += __shfl_xor(qp, 16, 64);
        sp += __shfl_xor(sp, 32, 64); qp += __shfl_xor(qp, 32, 64);
        if (q == 0) {
            sS[w * 64 + f] = sp;
            sQ[w * 64 + f] = qp;
        }
    }
    __syncthreads();
    if (tid < 64) {
        float S = sS[tid] + sS[64 + tid] + sS[128 + tid] + sS[192 + tid];
        atomicAdd(&stats[tid], S);
    } else if (tid < 128) {
        int f = tid - 64;
        float Q = sQ[f] + sQ[64 + f] + sQ[128 + f] + sQ[192 + f];
        atomicAdd(&stats[64 + f], Q);
    }
}

// ---------------- pooling (BN3 fused) + final GEMV ----------------
__device__ __forceinline__ int lower_bound_dev(const int* a, int n, int key) {
    int lo = 0, hi = n;
    while (lo < hi) {
        int mid = (lo + hi) >> 1;
        if (a[mid] < key) lo = mid + 1; else hi = mid;
    }
    return lo;
}

__global__ __launch_bounds__(256) void k_pool(const float4* __restrict__ x4,
                                              const int* __restrict__ batch,
                                              const float* __restrict__ stats,
                                              const float* __restrict__ gamma,
                                              const float* __restrict__ beta,
                                              const float* __restrict__ Wf,
                                              const float* __restrict__ bf,
                                              float* __restrict__ out,
                                              int nNodes, float invN) {
    int wid = threadIdx.x >> 6;
    int lane = threadIdx.x & 63;
    int grp = lane >> 4;
    int l16 = lane & 15;
    int g = blockIdx.x * 4 + wid;

    float4 sc, sh;
    {
        float4 s  = ((const float4*)stats)[l16];
        float4 q  = ((const float4*)stats)[16 + l16];
        float4 ga = ((const float4*)gamma)[l16];
        float4 be = ((const float4*)beta)[l16];
        float m;
        m = s.x * invN; sc.x = ga.x * rsqrtf(q.x * invN - m * m + 1e-5f); sh.x = be.x - m * sc.x;
        m = s.y * invN; sc.y = ga.y * rsqrtf(q.y * invN - m * m + 1e-5f); sh.y = be.y - m * sc.y;
        m = s.z * invN; sc.z = ga.z * rsqrtf(q.z * invN - m * m + 1e-5f); sh.z = be.z - m * sc.z;
        m = s.w * invN; sc.w = ga.w * rsqrtf(q.w * invN - m * m + 1e-5f); sh.w = be.w - m * sc.w;
    }

    int lo = lower_bound_dev(batch, nNodes, g);
    int hi = lower_bound_dev(batch, nNodes, g + 1);

    float4 acc = f4zero();
    for (int r = lo + grp; r < hi; r += 4) {
        float4 v = x4[(size_t)r * 16 + l16];
        acc.x += fmaxf(fmaf(v.x, sc.x, sh.x), 0.f);
        acc.y += fmaxf(fmaf(v.y, sc.y, sh.y), 0.f);
        acc.z += fmaxf(fmaf(v.z, sc.z, sh.z), 0.f);
        acc.w += fmaxf(fmaf(v.w, sc.w, sh.w), 0.f);
    }
    acc.x += __shfl_xor(acc.x, 16, 64); acc.y += __shfl_xor(acc.y, 16, 64);
    acc.z += __shfl_xor(acc.z, 16, 64); acc.w += __shfl_xor(acc.w, 16, 64);
    acc.x += __shfl_xor(acc.x, 32, 64); acc.y += __shfl_xor(acc.y, 32, 64);
    acc.z += __shfl_xor(acc.z, 32, 64); acc.w += __shfl_xor(acc.w, 32, 64);

    float4 wf = ((const float4*)Wf)[l16];
    float p = acc.x * wf.x + acc.y * wf.y + acc.z * wf.z + acc.w * wf.w;
    p += __shfl_xor(p, 1, 64);
    p += __shfl_xor(p, 2, 64);
    p += __shfl_xor(p, 4, 64);
    p += __shfl_xor(p, 8, 64);
    if (lane == 0) out[g] = p + bf[0];
}

extern "C" void kernel_launch(void* const* d_in, const int* in_sizes, int n_in,
                              void* d_out, int out_size, void* d_ws, size_t ws_size,
                              hipStream_t stream) {
    const float* x_in  = (const float*)d_in[0];
    const int*   ei    = (const int*)d_in[1];
    const int*   batch = (const int*)d_in[2];
    const float* W1    = (const float*)d_in[3];
    const float* b1    = (const float*)d_in[4];
    const float* W2    = (const float*)d_in[5];
    const float* b2    = (const float*)d_in[6];
    const float* gamma = (const float*)d_in[7];
    const float* beta  = (const float*)d_in[8];
    const float* Wf    = (const float*)d_in[9];
    const float* bf    = (const float*)d_in[10];

    const int nNodes = in_sizes[0] / HIDDEN_C;   // 50000 (pack assumes <= 65536)
    const int nE = in_sizes[1] / 2;              // 800000
    const int* src = ei;
    const int* dst = ei + nE;

    const int nBuckets = (nNodes + 63) / 64;         // 782
    const int nTot = nBuckets * NCHUNK;              // 200192
    const int chunkSz = (nE + NCHUNK - 1) / NCHUNK;  // 3125
    const int scanBlocks = (nTot + 1023) / 1024;     // 196 (<=256)
    const float invN = 1.f / (float)nNodes;

    const size_t NB = (size_t)nNodes * HIDDEN_C * sizeof(float);  // 12.8 MB
    char* ws = (char*)d_ws;
    float*    bufA    = (float*)ws;
    float*    bufB    = (float*)(ws + NB);
    float*    stats   = (float*)(ws + 2 * NB);              // 3 x 128 floats (4KB pad)
    unsigned short* wtbuf = (unsigned short*)(ws + 2 * NB + 4096);   // 6 x 8192 u16 = 96KB
    int*      rowptr  = (int*)(ws + 2 * NB + 4096 + 98304); // nNodes+1
    int*      partial = rowptr + nNodes + 64;               // 256
    int*      col     = partial + 256;                      // nE
    // transient CSR-build scratch aliased into bufB (bufB first written at layer-1 agg)
    unsigned* ebuf    = (unsigned*)bufB;                    // nE (3.2MB)
    int*      cnt     = (int*)((char*)bufB + (size_t)nE * 4);  // nTot (0.8MB)
    int*      eoff    = cnt + nTot + 64;                    // nTot (0.8MB)

    const int mlpGrid = nBuckets;
    const int aggGrid = (nNodes + 3) / 4;

    // ---- weight prep (once) + CSR build via 64-node buckets ----
    k_wprep<<<6, 256, 0, stream>>>(W1, W2, wtbuf);
    k_bcount<<<NCHUNK, 256, 0, stream>>>(dst, cnt, stats, nE, chunkSz, nBuckets);
    k_blocksum<<<scanBlocks, 256, 0, stream>>>(cnt, partial, nTot);
    k_scanpartial<<<1, 256, 0, stream>>>(partial, rowptr + nNodes, scanBlocks, nE);
    k_writeptr<<<scanBlocks, 256, 0, stream>>>(cnt, partial, eoff, nTot);
    k_bscatter<<<NCHUNK, 256, 0, stream>>>(src, dst, eoff, ebuf, nE, chunkSz, nBuckets);
    k_bfill<<<nBuckets, 256, 0, stream>>>(ebuf, eoff, rowptr, col, nNodes, nE, nBuckets);

    // ---- 3 layers: agg (fp32) + MFMA MLP (split bf16, precomputed W^T) ----
    const float* prev_h = x_in;
    float* cur = bufA;
    for (int i = 0; i < 3; ++i) {
        if (i == 0) {
            k_aggbn<false><<<aggGrid, 256, 0, stream>>>((const float4*)prev_h, rowptr, col,
                                                        nullptr, nullptr, nullptr,
                                                        (float4*)cur, nNodes, invN);
        } else {
            k_aggbn<true><<<aggGrid, 256, 0, stream>>>((const float4*)prev_h, rowptr, col,
                                                       stats + (size_t)(i - 1) * 128,
                                                       gamma + (size_t)(i - 1) * 64,
                                                       beta + (size_t)(i - 1) * 64,
                                                       (float4*)cur, nNodes, invN);
        }
        k_mlp<<<mlpGrid, 256, 0, stream>>>(cur, cur,
                                           wtbuf + (size_t)(2 * i) * 8192, b1 + (size_t)i * 64,
                                           wtbuf + (size_t)(2 * i + 1) * 8192, b2 + (size_t)i * 64,
                                           stats + (size_t)i * 128, nNodes);
        prev_h = cur;
        cur = (cur == bufA) ? bufB : bufA;
    }

    k_pool<<<64, 256, 0, stream>>>((const float4*)prev_h, batch,
                                   stats + 256, gamma + 128, beta + 128,
                                   Wf, bf, (float*)d_out, nNodes, invN);
}